// Round 1
// baseline (5193.045 us; speedup 1.0000x reference)
//
#include <hip/hip_runtime.h>
#include <hip/hip_bf16.h>

#define D 256
#define H 4
#define DPH 64

// ---------------------------------------------------------------------------
// Per-token label-routed projection: out[m] = x[m] @ W[lbl[m]] + b[lbl[m]]
// One block per token, 256 threads, thread o computes output dim o.
// ---------------------------------------------------------------------------
__global__ __launch_bounds__(256) void proj_kernel(
    const float* __restrict__ x, const float* __restrict__ W,
    const float* __restrict__ b, const int* __restrict__ lbl,
    float* __restrict__ out, int ntok) {
  int m = blockIdx.x;
  int o = threadIdx.x;
  __shared__ float xs[D];
  xs[o] = x[m * D + o];
  __syncthreads();
  int l = lbl[m];
  const float* Wl = W + (size_t)l * D * D;
  float acc = 0.f;
#pragma unroll 8
  for (int d = 0; d < D; ++d) acc += xs[d] * Wl[d * D + o];
  out[m * D + o] = acc + b[l * D + o];
}

// ---------------------------------------------------------------------------
// Masked flash attention. One thread per (head, query). grid=(H, M/256),
// block=256. K/V tiles (32 keys x 64 dims) staged in LDS.
// ---------------------------------------------------------------------------
__global__ __launch_bounds__(256) void attn_kernel(
    const float* __restrict__ qb, const float* __restrict__ kb,
    const float* __restrict__ vb, const int* __restrict__ lbl1,
    const int* __restrict__ lbl2, float* __restrict__ ctxb, int nkey) {
  const int h = blockIdx.x;
  const int m = blockIdx.y * 256 + threadIdx.x;
  const int t = threadIdx.x;

  __shared__ float ks[32][DPH];
  __shared__ float vs[32][DPH];
  __shared__ int ls[32];

  float q[DPH];
#pragma unroll
  for (int d = 0; d < DPH; ++d) q[d] = qb[m * D + h * DPH + d];
  const int myl = lbl2[m];

  float ctx[DPH];
#pragma unroll
  for (int d = 0; d < DPH; ++d) ctx[d] = 0.f;
  float mrun = -3.4e38f, lrun = 0.f;

  for (int n0 = 0; n0 < nkey; n0 += 32) {
    __syncthreads();
#pragma unroll
    for (int i = 0; i < 8; ++i) {
      int idx = t + i * 256;       // 0..2047
      int kk = idx >> 6, d = idx & 63;
      ks[kk][d] = kb[(n0 + kk) * D + h * DPH + d];
      vs[kk][d] = vb[(n0 + kk) * D + h * DPH + d];
    }
    if (t < 32) ls[t] = lbl1[n0 + t];
    __syncthreads();

    for (int kk = 0; kk < 32; ++kk) {
      if (ls[kk] != myl) continue;   // divergent: ~1/9 lanes active
      float s = 0.f;
#pragma unroll
      for (int d = 0; d < DPH; ++d) s += q[d] * ks[kk][d];
      s *= 0.25f;  // scale = (DPH // H)^-0.5 = 16^-0.5
      float mnew = fmaxf(mrun, s);
      float p = __expf(s - mnew);
      float alpha = __expf(mrun - mnew);
      lrun = lrun * alpha + p;
#pragma unroll
      for (int d = 0; d < DPH; ++d) ctx[d] = ctx[d] * alpha + p * vs[kk][d];
      mrun = mnew;
    }
  }

  float inv = (lrun > 0.f) ? (1.f / lrun) : 0.f;
#pragma unroll
  for (int d = 0; d < DPH; ++d) ctxb[m * D + h * DPH + d] = ctx[d] * inv;
}

// ---------------------------------------------------------------------------
// out = LN(query + ctx @ Wf + bf) * gamma + beta. One block per token.
// ---------------------------------------------------------------------------
__device__ inline float wave_sum(float v) {
#pragma unroll
  for (int off = 32; off > 0; off >>= 1) v += __shfl_down(v, off, 64);
  return v;
}

__global__ __launch_bounds__(256) void out_kernel(
    const float* __restrict__ ctxb, const float* __restrict__ query,
    const float* __restrict__ Wf, const float* __restrict__ bf,
    const float* __restrict__ gamma, const float* __restrict__ beta,
    float* __restrict__ out) {
  int m = blockIdx.x;
  int o = threadIdx.x;
  __shared__ float xs[D];
  __shared__ float red[8];
  xs[o] = ctxb[m * D + o];
  __syncthreads();
  float acc = 0.f;
#pragma unroll 8
  for (int d = 0; d < D; ++d) acc += xs[d] * Wf[d * D + o];
  float res = query[m * D + o] + acc + bf[o];

  int wid = o >> 6, lane = o & 63;
  float s = wave_sum(res);
  if (lane == 0) red[wid] = s;
  __syncthreads();
  float mu = (red[0] + red[1] + red[2] + red[3]) * (1.f / D);
  float dv = (res - mu) * (res - mu);
  float s2 = wave_sum(dv);
  if (lane == 0) red[4 + wid] = s2;
  __syncthreads();
  float var = (red[4] + red[5] + red[6] + red[7]) * (1.f / D);
  out[m * D + o] = (res - mu) * rsqrtf(var + 1e-5f) * gamma[o] + beta[o];
}

// ---------------------------------------------------------------------------
extern "C" void kernel_launch(void* const* d_in, const int* in_sizes, int n_in,
                              void* d_out, int out_size, void* d_ws, size_t ws_size,
                              hipStream_t stream) {
  const float* key   = (const float*)d_in[0];
  const float* value = (const float*)d_in[1];
  const float* query = (const float*)d_in[2];
  const int*   lbl1  = (const int*)d_in[3];
  const int*   lbl2  = (const int*)d_in[4];
  const float* Wq = (const float*)d_in[5];
  const float* bq = (const float*)d_in[6];
  const float* Wk = (const float*)d_in[7];
  const float* bk = (const float*)d_in[8];
  const float* Wv = (const float*)d_in[9];
  const float* bv = (const float*)d_in[10];
  const float* Wf = (const float*)d_in[11];
  const float* bf = (const float*)d_in[12];
  const float* gamma = (const float*)d_in[13];
  const float* beta  = (const float*)d_in[14];
  float* out = (float*)d_out;

  const int N = in_sizes[0] / D;  // keys
  const int M = in_sizes[2] / D;  // queries

  float* ws = (float*)d_ws;
  float* qbuf = ws;
  float* kbuf = qbuf + (size_t)M * D;
  float* vbuf = kbuf + (size_t)N * D;
  float* cbuf = vbuf + (size_t)N * D;

  proj_kernel<<<M, 256, 0, stream>>>(query, Wq, bq, lbl2, qbuf, M);
  proj_kernel<<<N, 256, 0, stream>>>(key,   Wk, bk, lbl1, kbuf, N);
  proj_kernel<<<N, 256, 0, stream>>>(value, Wv, bv, lbl1, vbuf, N);

  dim3 agrid(H, M / 256);
  attn_kernel<<<agrid, 256, 0, stream>>>(qbuf, kbuf, vbuf, lbl1, lbl2, cbuf, N);

  out_kernel<<<M, 256, 0, stream>>>(cbuf, query, Wf, bf, gamma, beta, out);
}

// Round 2
// 825.996 us; speedup vs baseline: 6.2870x; 6.2870x over previous
//
#include <hip/hip_runtime.h>
#include <hip/hip_bf16.h>

#define D 256
#define H 4
#define DPH 64
#define NLBL 9
#define KT 64

// ---------------------------------------------------------------------------
// Per-token label-routed projection: out[m] = x[m] @ W[lbl[m]] + b[lbl[m]]
// ---------------------------------------------------------------------------
__global__ __launch_bounds__(256) void proj_kernel(
    const float* __restrict__ x, const float* __restrict__ W,
    const float* __restrict__ b, const int* __restrict__ lbl,
    float* __restrict__ out, int ntok) {
  int m = blockIdx.x;
  int o = threadIdx.x;
  __shared__ float xs[D];
  xs[o] = x[m * D + o];
  __syncthreads();
  int l = lbl[m];
  const float* Wl = W + (size_t)l * D * D;
  float acc = 0.f;
#pragma unroll 8
  for (int d = 0; d < D; ++d) acc += xs[d] * Wl[d * D + o];
  out[m * D + o] = acc + b[l * D + o];
}

// ---------------------------------------------------------------------------
// Label bucketing: histogram -> exclusive prefix -> stable scatter.
// cnt[0..8] = key labels, cnt[9..17] = query labels.
// off[0..9] = key offsets, off[10..19] = query offsets.
// ---------------------------------------------------------------------------
__global__ __launch_bounds__(256) void count_kernel(
    const int* __restrict__ lbl1, int n1, const int* __restrict__ lbl2, int n2,
    int* __restrict__ cnt) {
  int t = blockIdx.x * 256 + threadIdx.x;
  if (t < n1) atomicAdd(&cnt[lbl1[t]], 1);
  else if (t < n1 + n2) atomicAdd(&cnt[NLBL + lbl2[t - n1]], 1);
}

__global__ void offsets_kernel(const int* __restrict__ cnt, int* __restrict__ off) {
  if (threadIdx.x == 0) {
    int a0 = 0, a1 = 0;
    for (int i = 0; i < NLBL; ++i) {
      off[i] = a0;      a0 += cnt[i];
      off[10 + i] = a1; a1 += cnt[NLBL + i];
    }
    off[NLBL] = a0; off[10 + NLBL] = a1;
  }
}

__global__ __launch_bounds__(256) void scatter_kernel(
    const int* __restrict__ lbl1, int n1, const int* __restrict__ lbl2, int n2,
    const int* __restrict__ off, int* __restrict__ korder, int* __restrict__ qorder) {
  const int l = blockIdx.x;          // label
  const int a = blockIdx.y;          // 0: keys, 1: queries
  const int n = (a == 0) ? n1 : n2;
  const int* lbl = (a == 0) ? lbl1 : lbl2;
  int* order = (a == 0) ? korder : qorder;
  const int base = off[a * 10 + l];

  const int t = threadIdx.x, wave = t >> 6, lane = t & 63;
  __shared__ int wtot[4];
  int pos = 0;
  for (int chunk = 0; chunk < n; chunk += 256) {
    int i = chunk + t;
    bool flag = (i < n) && (lbl[i] == l);
    unsigned long long bal = __ballot(flag);
    int wprefix = __popcll(bal & ((1ull << lane) - 1ull));
    if (lane == 0) wtot[wave] = __popcll(bal);
    __syncthreads();
    int prew = 0;
#pragma unroll
    for (int w = 0; w < 4; ++w) prew += (w < wave) ? wtot[w] : 0;
    int tot = wtot[0] + wtot[1] + wtot[2] + wtot[3];
    if (flag) order[base + pos + prew + wprefix] = i;
    pos += tot;
    __syncthreads();
  }
}

// ---------------------------------------------------------------------------
// Dense per-label-group flash attention.
// grid = (ceil(M/128), H, NLBL), block = 256 (4 waves).
// Each wave owns 32 queries; 2 threads per query, 32 dims each.
// K/V tiles of 64 keys gathered into LDS via korder.
// ---------------------------------------------------------------------------
__global__ __launch_bounds__(256) void attn_grouped(
    const float* __restrict__ qb, const float* __restrict__ kb,
    const float* __restrict__ vb, const int* __restrict__ qorder,
    const int* __restrict__ korder, const int* __restrict__ off,
    const int* __restrict__ cnt, float* __restrict__ ctxb) {
  const int l = blockIdx.z, h = blockIdx.y;
  const int nq = cnt[NLBL + l], nk = cnt[l];
  const int qtile = blockIdx.x * 128;
  if (qtile >= nq) return;
  const int qoff = off[10 + l], koff = off[l];

  const int t = threadIdx.x, wave = t >> 6, lane = t & 63;
  const int ql = qtile + wave * 32 + (lane >> 1);
  const int half = lane & 1;
  const bool valid = ql < nq;
  const int qi = valid ? qorder[qoff + ql] : 0;

  float q[32], ctx[32];
  const float* qp = qb + (size_t)qi * D + h * DPH + half * 32;
#pragma unroll
  for (int j = 0; j < 32; ++j) {
    q[j] = valid ? qp[j] : 0.f;
    ctx[j] = 0.f;
  }
  float mrun = -3.4e38f, lrun = 0.f;

  __shared__ float ks[KT][DPH];
  __shared__ float vs[KT][DPH];
  __shared__ int kidx[KT];

  for (int n0 = 0; n0 < nk; n0 += KT) {
    const int nk_t = min(KT, nk - n0);
    __syncthreads();
    if (t < KT) kidx[t] = (t < nk_t) ? korder[koff + n0 + t] : 0;
    __syncthreads();
#pragma unroll
    for (int i = 0; i < 16; ++i) {
      int e = t + i * 256;
      int kk = e >> 6, d = e & 63;
      if (kk < nk_t) {
        size_t src = (size_t)kidx[kk] * D + h * DPH + d;
        ks[kk][d] = kb[src];
        vs[kk][d] = vb[src];
      }
    }
    __syncthreads();
    for (int kk = 0; kk < nk_t; ++kk) {
      float s = 0.f;
      const float* krow = &ks[kk][half * 32];
#pragma unroll
      for (int j = 0; j < 32; ++j) s += q[j] * krow[j];
      s += __shfl_xor(s, 1, 64);
      s *= 0.25f;  // scale = (DPH // H)^-0.5
      float mnew = fmaxf(mrun, s);
      float p = __expf(s - mnew);
      float alpha = __expf(mrun - mnew);
      lrun = lrun * alpha + p;
      const float* vrow = &vs[kk][half * 32];
#pragma unroll
      for (int j = 0; j < 32; ++j) ctx[j] = ctx[j] * alpha + p * vrow[j];
      mrun = mnew;
    }
  }

  if (valid) {
    float inv = (lrun > 0.f) ? (1.f / lrun) : 0.f;
    float* op = ctxb + (size_t)qi * D + h * DPH + half * 32;
#pragma unroll
    for (int j = 0; j < 32; ++j) op[j] = ctx[j] * inv;
  }
}

// ---------------------------------------------------------------------------
// out = LN(query + ctx @ Wf + bf) * gamma + beta. One block per token.
// ---------------------------------------------------------------------------
__device__ inline float wave_sum(float v) {
#pragma unroll
  for (int off = 32; off > 0; off >>= 1) v += __shfl_down(v, off, 64);
  return v;
}

__global__ __launch_bounds__(256) void out_kernel(
    const float* __restrict__ ctxb, const float* __restrict__ query,
    const float* __restrict__ Wf, const float* __restrict__ bf,
    const float* __restrict__ gamma, const float* __restrict__ beta,
    float* __restrict__ out) {
  int m = blockIdx.x;
  int o = threadIdx.x;
  __shared__ float xs[D];
  __shared__ float red[8];
  xs[o] = ctxb[m * D + o];
  __syncthreads();
  float acc = 0.f;
#pragma unroll 8
  for (int d = 0; d < D; ++d) acc += xs[d] * Wf[d * D + o];
  float res = query[m * D + o] + acc + bf[o];

  int wid = o >> 6, lane = o & 63;
  float s = wave_sum(res);
  if (lane == 0) red[wid] = s;
  __syncthreads();
  float mu = (red[0] + red[1] + red[2] + red[3]) * (1.f / D);
  float dv = (res - mu) * (res - mu);
  float s2 = wave_sum(dv);
  if (lane == 0) red[4 + wid] = s2;
  __syncthreads();
  float var = (red[4] + red[5] + red[6] + red[7]) * (1.f / D);
  out[m * D + o] = (res - mu) * rsqrtf(var + 1e-5f) * gamma[o] + beta[o];
}

// ---------------------------------------------------------------------------
extern "C" void kernel_launch(void* const* d_in, const int* in_sizes, int n_in,
                              void* d_out, int out_size, void* d_ws, size_t ws_size,
                              hipStream_t stream) {
  const float* key   = (const float*)d_in[0];
  const float* value = (const float*)d_in[1];
  const float* query = (const float*)d_in[2];
  const int*   lbl1  = (const int*)d_in[3];
  const int*   lbl2  = (const int*)d_in[4];
  const float* Wq = (const float*)d_in[5];
  const float* bq = (const float*)d_in[6];
  const float* Wk = (const float*)d_in[7];
  const float* bk = (const float*)d_in[8];
  const float* Wv = (const float*)d_in[9];
  const float* bv = (const float*)d_in[10];
  const float* Wf = (const float*)d_in[11];
  const float* bf = (const float*)d_in[12];
  const float* gamma = (const float*)d_in[13];
  const float* beta  = (const float*)d_in[14];
  float* out = (float*)d_out;

  const int N = in_sizes[0] / D;  // keys
  const int M = in_sizes[2] / D;  // queries

  // Workspace layout: int header (cnt/off/korder/qorder), then float buffers.
  int* cnt = (int*)d_ws;            // 18 used (pad to 32)
  int* off = cnt + 32;              // 20 used (pad to 32)
  int* korder = off + 32;           // N
  int* qorder = korder + N;         // M
  size_t ihdr_bytes = ((size_t)(64 + N + M) * sizeof(int) + 255) & ~(size_t)255;
  float* qbuf = (float*)((char*)d_ws + ihdr_bytes);
  float* kbuf = qbuf + (size_t)M * D;
  float* vbuf = kbuf + (size_t)N * D;
  float* cbuf = vbuf + (size_t)N * D;

  hipMemsetAsync(cnt, 0, 18 * sizeof(int), stream);
  count_kernel<<<(N + M + 255) / 256, 256, 0, stream>>>(lbl1, N, lbl2, M, cnt);
  offsets_kernel<<<1, 64, 0, stream>>>(cnt, off);
  dim3 sgrid(NLBL, 2);
  scatter_kernel<<<sgrid, 256, 0, stream>>>(lbl1, N, lbl2, M, off, korder, qorder);

  proj_kernel<<<M, 256, 0, stream>>>(query, Wq, bq, lbl2, qbuf, M);
  proj_kernel<<<N, 256, 0, stream>>>(key,   Wk, bk, lbl1, kbuf, N);
  proj_kernel<<<N, 256, 0, stream>>>(value, Wv, bv, lbl1, vbuf, N);

  dim3 agrid((M + 127) / 128, H, NLBL);
  attn_grouped<<<agrid, 256, 0, stream>>>(qbuf, kbuf, vbuf, qorder, korder,
                                          off, cnt, cbuf);

  out_kernel<<<M, 256, 0, stream>>>(cbuf, query, Wf, bf, gamma, beta, out);
}

// Round 3
// 761.072 us; speedup vs baseline: 6.8233x; 1.0853x over previous
//
#include <hip/hip_runtime.h>
#include <hip/hip_bf16.h>

#define D 256
#define H 4
#define DPH 64
#define NLBL 9

typedef __attribute__((ext_vector_type(8))) __bf16 bf16x8;
typedef __attribute__((ext_vector_type(4))) float f32x4;

// ---------------------------------------------------------------------------
// Label bucketing: histogram -> offsets/padded offsets/tile tables -> scatter.
// cnt[0..8]=key labels, cnt[9..17]=query labels.
// off[0..9]=key seg offsets, off[10..19]=query seg offsets (unpadded).
// pko/pqo[0..9]: padded (64-aligned) segment offsets. tq/tk: tile->(label,row0).
// ---------------------------------------------------------------------------
__global__ __launch_bounds__(256) void count_kernel(
    const int* __restrict__ lbl1, int n1, const int* __restrict__ lbl2, int n2,
    int* __restrict__ cnt) {
  int t = blockIdx.x * 256 + threadIdx.x;
  if (t < n1) atomicAdd(&cnt[lbl1[t]], 1);
  else if (t < n1 + n2) atomicAdd(&cnt[NLBL + lbl2[t - n1]], 1);
}

__global__ void offsets_kernel(const int* __restrict__ cnt, int* __restrict__ off,
                               int* __restrict__ pqo, int* __restrict__ pko,
                               int* __restrict__ tq, int* __restrict__ tk,
                               int* __restrict__ ntl) {
  if (threadIdx.x != 0) return;
  int a0 = 0, a1 = 0, p0 = 0, p1 = 0, t0 = 0, t1 = 0;
  for (int l = 0; l < NLBL; ++l) {
    off[l] = a0;      a0 += cnt[l];
    off[10 + l] = a1; a1 += cnt[NLBL + l];
    pko[l] = p0; pqo[l] = p1;
    int tkl = (cnt[l] + 63) >> 6, tql = (cnt[NLBL + l] + 63) >> 6;
    for (int i = 0; i < tkl; ++i) { tk[2 * t0] = l; tk[2 * t0 + 1] = p0 + (i << 6); ++t0; }
    for (int i = 0; i < tql; ++i) { tq[2 * t1] = l; tq[2 * t1 + 1] = p1 + (i << 6); ++t1; }
    p0 += tkl << 6; p1 += tql << 6;
  }
  off[9] = a0; off[19] = a1; pko[9] = p0; pqo[9] = p1;
  ntl[0] = t1; ntl[1] = t0;
}

__global__ __launch_bounds__(256) void scatter_kernel(
    const int* __restrict__ lbl1, int n1, const int* __restrict__ lbl2, int n2,
    const int* __restrict__ off, int* __restrict__ korder, int* __restrict__ qorder) {
  const int l = blockIdx.x;
  const int a = blockIdx.y;
  const int n = (a == 0) ? n1 : n2;
  const int* lbl = (a == 0) ? lbl1 : lbl2;
  int* order = (a == 0) ? korder : qorder;
  const int base = off[a * 10 + l];

  const int t = threadIdx.x, wave = t >> 6, lane = t & 63;
  __shared__ int wtot[4];
  int pos = 0;
  for (int chunk = 0; chunk < n; chunk += 256) {
    int i = chunk + t;
    bool flag = (i < n) && (lbl[i] == l);
    unsigned long long bal = __ballot(flag);
    int wprefix = __popcll(bal & ((1ull << lane) - 1ull));
    if (lane == 0) wtot[wave] = __popcll(bal);
    __syncthreads();
    int prew = 0;
#pragma unroll
    for (int w = 0; w < 4; ++w) prew += (w < wave) ? wtot[w] : 0;
    int tot = wtot[0] + wtot[1] + wtot[2] + wtot[3];
    if (flag) order[base + pos + prew + wprefix] = i;
    pos += tot;
    __syncthreads();
  }
}

// ---------------------------------------------------------------------------
// Transpose+cast weights: Wt[n][k] = bf16(W[k][n]). 28 matrices (9q,9k,9v,1f),
// grid=(16 subtiles, 28), 64x64 subtile per block via LDS.
// ---------------------------------------------------------------------------
__global__ __launch_bounds__(256) void transW_kernel(
    const float* __restrict__ Wq, const float* __restrict__ Wk,
    const float* __restrict__ Wv, const float* __restrict__ Wf,
    __bf16* __restrict__ Wqt, __bf16* __restrict__ Wkt,
    __bf16* __restrict__ Wvt, __bf16* __restrict__ Wft) {
  int m = blockIdx.y, sub = blockIdx.x;
  const float* src; __bf16* dst;
  if (m < 9)       { src = Wq + (size_t)m * 65536;        dst = Wqt + (size_t)m * 65536; }
  else if (m < 18) { src = Wk + (size_t)(m - 9) * 65536;  dst = Wkt + (size_t)(m - 9) * 65536; }
  else if (m < 27) { src = Wv + (size_t)(m - 18) * 65536; dst = Wvt + (size_t)(m - 18) * 65536; }
  else             { src = Wf;                            dst = Wft; }
  int k0 = (sub >> 2) << 6, n0 = (sub & 3) << 6;
  __shared__ float lds[64][65];
  int t = threadIdx.x, rr = t >> 6, c = t & 63;
#pragma unroll
  for (int i = 0; i < 16; ++i) {
    int r = i * 4 + rr;
    lds[r][c] = src[(size_t)(k0 + r) * D + n0 + c];
  }
  __syncthreads();
#pragma unroll
  for (int i = 0; i < 16; ++i) {
    int r = i * 4 + rr;
    dst[(size_t)(n0 + r) * D + k0 + c] = (__bf16)lds[c][r];
  }
}

// ---------------------------------------------------------------------------
// Label-routed input projections via MFMA bf16. Tile: 64 rows x 256 cols,
// block=256 (4 waves, wave w owns cols [64w,64w+64)). A gathered from fp32
// input rows (order[]), cast to bf16 in-reg. B from pre-transposed Wt[n][k].
// grid=(tile_cap, 3): y=0 query->qbuf, y=1 key->kbuf, y=2 value->vbuf.
// Output fp32, sorted-padded rows (pad rows get bias only).
// ---------------------------------------------------------------------------
__global__ __launch_bounds__(256) void gemm_in_kernel(
    const float* __restrict__ query, const float* __restrict__ key,
    const float* __restrict__ value,
    const __bf16* __restrict__ Wqt, const __bf16* __restrict__ Wkt,
    const __bf16* __restrict__ Wvt,
    const float* __restrict__ bq, const float* __restrict__ bk,
    const float* __restrict__ bv,
    const int* __restrict__ qorder, const int* __restrict__ korder,
    const int* __restrict__ off, const int* __restrict__ cnt,
    const int* __restrict__ pqo, const int* __restrict__ pko,
    const int* __restrict__ tq, const int* __restrict__ tk,
    const int* __restrict__ ntl,
    float* __restrict__ qbuf, float* __restrict__ kbuf, float* __restrict__ vbuf) {
  const int y = blockIdx.y;
  const int nt = (y == 0) ? ntl[0] : ntl[1];
  if ((int)blockIdx.x >= nt) return;
  const int* tt = (y == 0) ? tq : tk;
  const float* x = (y == 0) ? query : (y == 1 ? key : value);
  const __bf16* W = (y == 0) ? Wqt : (y == 1 ? Wkt : Wvt);
  const float* bias = (y == 0) ? bq : (y == 1 ? bk : bv);
  const int* order = (y == 0) ? qorder : korder;
  const int* po = (y == 0) ? pqo : pko;
  float* outp = (y == 0) ? qbuf : (y == 1 ? kbuf : vbuf);

  const int l = tt[2 * blockIdx.x], prow0 = tt[2 * blockIdx.x + 1];
  const int cl = (y == 0) ? cnt[NLBL + l] : cnt[l];
  const int ooff = (y == 0) ? off[10 + l] : off[l];
  const int base = prow0 - po[l];

  const int t = threadIdx.x, w = t >> 6, lane = t & 63;
  const int lr = lane & 15, lk = lane >> 4;

  int src[4];
#pragma unroll
  for (int fi = 0; fi < 4; ++fi) {
    int ridx = base + fi * 16 + lr;
    src[fi] = (ridx < cl) ? order[ooff + ridx] : -1;
  }

  bf16x8 az;
#pragma unroll
  for (int j = 0; j < 8; ++j) az[j] = (__bf16)0.f;

  f32x4 acc[4][4];
#pragma unroll
  for (int i = 0; i < 4; ++i)
#pragma unroll
    for (int j = 0; j < 4; ++j) acc[i][j] = (f32x4){0.f, 0.f, 0.f, 0.f};

  for (int kb = 0; kb < 8; ++kb) {
    const int kbase = kb * 32 + lk * 8;
    bf16x8 a[4], b[4];
#pragma unroll
    for (int fi = 0; fi < 4; ++fi) {
      if (src[fi] >= 0) {
        const float* ap = x + (size_t)src[fi] * D + kbase;
        float4 u0 = *(const float4*)ap;
        float4 u1 = *(const float4*)(ap + 4);
        a[fi][0] = (__bf16)u0.x; a[fi][1] = (__bf16)u0.y;
        a[fi][2] = (__bf16)u0.z; a[fi][3] = (__bf16)u0.w;
        a[fi][4] = (__bf16)u1.x; a[fi][5] = (__bf16)u1.y;
        a[fi][6] = (__bf16)u1.z; a[fi][7] = (__bf16)u1.w;
      } else {
        a[fi] = az;
      }
    }
#pragma unroll
    for (int fj = 0; fj < 4; ++fj) {
      int col = w * 64 + fj * 16 + lr;
      b[fj] = *(const bf16x8*)(W + (size_t)l * 65536 + (size_t)col * D + kbase);
    }
#pragma unroll
    for (int fi = 0; fi < 4; ++fi)
#pragma unroll
      for (int fj = 0; fj < 4; ++fj)
        acc[fi][fj] = __builtin_amdgcn_mfma_f32_16x16x32_bf16(a[fi], b[fj], acc[fi][fj], 0, 0, 0);
  }

#pragma unroll
  for (int fj = 0; fj < 4; ++fj) {
    int col = w * 64 + fj * 16 + lr;
    float bv_ = bias[l * D + col];
#pragma unroll
    for (int fi = 0; fi < 4; ++fi)
#pragma unroll
      for (int r = 0; r < 4; ++r) {
        int row = prow0 + fi * 16 + lk * 4 + r;
        outp[(size_t)row * D + col] = acc[fi][fj][r] + bv_;
      }
  }
}

// ---------------------------------------------------------------------------
// Grouped attention, fp32, tile-batched online softmax.
// grid=(ceil(M/64), H, NLBL), block=256 (4 waves; wave=16 queries, 4 thr/query
// x 16 dims). K/V contiguous (sorted-padded), 32-key tiles staged in LDS.
// Output ctx as bf16 into cg (sorted-padded rows; pads zeroed).
// ---------------------------------------------------------------------------
__global__ __launch_bounds__(256) void attn_kernel(
    const float* __restrict__ qbuf, const float* __restrict__ kbuf,
    const float* __restrict__ vbuf, const int* __restrict__ cnt,
    const int* __restrict__ pqo, const int* __restrict__ pko,
    __bf16* __restrict__ cg) {
  const int l = blockIdx.z, h = blockIdx.y;
  const int nq = cnt[NLBL + l], nk = cnt[l];
  const int qtile = blockIdx.x * 64;
  if (qtile >= nq) return;
  const int t = threadIdx.x, w = t >> 6, lane = t & 63;
  const int qq = w * 16 + (lane >> 2);
  const int qr = lane & 3;
  const int prow = pqo[l] + qtile + qq;
  const bool valid = (qtile + qq) < nq;

  float q[16];
  {
    const float* qp = qbuf + (size_t)prow * D + h * DPH + qr * 16;
#pragma unroll
    for (int j = 0; j < 16; j += 4) {
      float4 u = *(const float4*)(qp + j);
      q[j] = u.x * 0.25f; q[j + 1] = u.y * 0.25f;
      q[j + 2] = u.z * 0.25f; q[j + 3] = u.w * 0.25f;
    }
  }
  float ctx[16];
#pragma unroll
  for (int j = 0; j < 16; ++j) ctx[j] = 0.f;
  float mrun = -3.4e38f, lrun = 0.f;

  __shared__ float ks[32][64];
  __shared__ float vs[32][64];
  const int kb0 = pko[l];

  for (int n0 = 0; n0 < nk; n0 += 32) {
    __syncthreads();
    {
      int e = t * 4;
      int kk = e >> 6, d = e & 63;
      const size_t rb = (size_t)(kb0 + n0) * D + h * DPH;
      *(float4*)&ks[kk][d]      = *(const float4*)(kbuf + rb + (size_t)kk * D + d);
      *(float4*)&ks[kk + 16][d] = *(const float4*)(kbuf + rb + (size_t)(kk + 16) * D + d);
      *(float4*)&vs[kk][d]      = *(const float4*)(vbuf + rb + (size_t)kk * D + d);
      *(float4*)&vs[kk + 16][d] = *(const float4*)(vbuf + rb + (size_t)(kk + 16) * D + d);
    }
    __syncthreads();
    const int nkt = min(32, nk - n0);
    float s[32];
#pragma unroll
    for (int kk = 0; kk < 32; ++kk) {
      float a = 0.f;
#pragma unroll
      for (int j = 0; j < 16; ++j) a += q[j] * ks[kk][qr * 16 + j];
      a += __shfl_xor(a, 1, 64);
      a += __shfl_xor(a, 2, 64);
      s[kk] = (kk < nkt) ? a : -3.4e38f;
    }
    float tm = s[0];
#pragma unroll
    for (int kk = 1; kk < 32; ++kk) tm = fmaxf(tm, s[kk]);
    float mnew = fmaxf(mrun, tm);
    float alpha = __expf(mrun - mnew);
    lrun *= alpha;
#pragma unroll
    for (int j = 0; j < 16; ++j) ctx[j] *= alpha;
#pragma unroll
    for (int kk = 0; kk < 32; ++kk) {
      float p = __expf(s[kk] - mnew);
      lrun += p;
#pragma unroll
      for (int j = 0; j < 16; ++j) ctx[j] += p * vs[kk][qr * 16 + j];
    }
    mrun = mnew;
  }

  float inv = (valid && lrun > 0.f) ? (1.f / lrun) : 0.f;
  __bf16* op = cg + (size_t)prow * D + h * DPH + qr * 16;
  bf16x8 o0, o1;
#pragma unroll
  for (int j = 0; j < 8; ++j) {
    o0[j] = (__bf16)(ctx[j] * inv);
    o1[j] = (__bf16)(ctx[8 + j] * inv);
  }
  *(bf16x8*)op = o0;
  *(bf16x8*)(op + 8) = o1;
}

// ---------------------------------------------------------------------------
// Output projection: rbuf = cg @ Wf + bf (sorted-padded rows). MFMA bf16.
// ---------------------------------------------------------------------------
__global__ __launch_bounds__(256) void gemm_out_kernel(
    const __bf16* __restrict__ cg, const __bf16* __restrict__ Wft,
    const float* __restrict__ bf_, const int* __restrict__ tq,
    const int* __restrict__ ntl, float* __restrict__ rbuf) {
  if ((int)blockIdx.x >= ntl[0]) return;
  const int prow0 = tq[2 * blockIdx.x + 1];
  const int t = threadIdx.x, w = t >> 6, lane = t & 63;
  const int lr = lane & 15, lk = lane >> 4;

  f32x4 acc[4][4];
#pragma unroll
  for (int i = 0; i < 4; ++i)
#pragma unroll
    for (int j = 0; j < 4; ++j) acc[i][j] = (f32x4){0.f, 0.f, 0.f, 0.f};

  for (int kb = 0; kb < 8; ++kb) {
    const int kbase = kb * 32 + lk * 8;
    bf16x8 a[4], b[4];
#pragma unroll
    for (int fi = 0; fi < 4; ++fi)
      a[fi] = *(const bf16x8*)(cg + (size_t)(prow0 + fi * 16 + lr) * D + kbase);
#pragma unroll
    for (int fj = 0; fj < 4; ++fj) {
      int col = w * 64 + fj * 16 + lr;
      b[fj] = *(const bf16x8*)(Wft + (size_t)col * D + kbase);
    }
#pragma unroll
    for (int fi = 0; fi < 4; ++fi)
#pragma unroll
      for (int fj = 0; fj < 4; ++fj)
        acc[fi][fj] = __builtin_amdgcn_mfma_f32_16x16x32_bf16(a[fi], b[fj], acc[fi][fj], 0, 0, 0);
  }

#pragma unroll
  for (int fj = 0; fj < 4; ++fj) {
    int col = w * 64 + fj * 16 + lr;
    float bv_ = bf_[col];
#pragma unroll
    for (int fi = 0; fi < 4; ++fi)
#pragma unroll
      for (int r = 0; r < 4; ++r) {
        int row = prow0 + fi * 16 + lk * 4 + r;
        rbuf[(size_t)row * D + col] = acc[fi][fj][r] + bv_;
      }
  }
}

// ---------------------------------------------------------------------------
// res = rbuf (proj+bias) + query[src]; LayerNorm; scatter to out[src].
// One block per padded-sorted row.
// ---------------------------------------------------------------------------
__device__ inline float wave_sum(float v) {
#pragma unroll
  for (int off = 32; off > 0; off >>= 1) v += __shfl_down(v, off, 64);
  return v;
}

__global__ __launch_bounds__(256) void ln_kernel(
    const float* __restrict__ rbuf, const float* __restrict__ query,
    const int* __restrict__ qorder, const int* __restrict__ off,
    const int* __restrict__ cnt, const int* __restrict__ pqo,
    const float* __restrict__ gamma, const float* __restrict__ beta,
    float* __restrict__ out) {
  int row = blockIdx.x;
  if (row >= pqo[9]) return;
  int l = 0;
#pragma unroll
  for (int i = 0; i < 8; ++i)
    if (row >= pqo[i + 1]) l = i + 1;
  int idx = row - pqo[l];
  if (idx >= cnt[NLBL + l]) return;
  int src = qorder[off[10 + l] + idx];

  int o = threadIdx.x;
  __shared__ float red[8];
  float res = rbuf[(size_t)row * D + o] + query[(size_t)src * D + o];

  int wid = o >> 6, lane = o & 63;
  float s = wave_sum(res);
  if (lane == 0) red[wid] = s;
  __syncthreads();
  float mu = (red[0] + red[1] + red[2] + red[3]) * (1.f / D);
  float dv = (res - mu) * (res - mu);
  float s2 = wave_sum(dv);
  if (lane == 0) red[4 + wid] = s2;
  __syncthreads();
  float var = (red[4] + red[5] + red[6] + red[7]) * (1.f / D);
  out[(size_t)src * D + o] = (res - mu) * rsqrtf(var + 1e-5f) * gamma[o] + beta[o];
}

// ---------------------------------------------------------------------------
extern "C" void kernel_launch(void* const* d_in, const int* in_sizes, int n_in,
                              void* d_out, int out_size, void* d_ws, size_t ws_size,
                              hipStream_t stream) {
  const float* key   = (const float*)d_in[0];
  const float* value = (const float*)d_in[1];
  const float* query = (const float*)d_in[2];
  const int*   lbl1  = (const int*)d_in[3];
  const int*   lbl2  = (const int*)d_in[4];
  const float* Wq = (const float*)d_in[5];
  const float* bq = (const float*)d_in[6];
  const float* Wk = (const float*)d_in[7];
  const float* bk = (const float*)d_in[8];
  const float* Wv = (const float*)d_in[9];
  const float* bv = (const float*)d_in[10];
  const float* Wf = (const float*)d_in[11];
  const float* bf_ = (const float*)d_in[12];
  const float* gamma = (const float*)d_in[13];
  const float* beta  = (const float*)d_in[14];
  float* out = (float*)d_out;

  const int N = in_sizes[0] / D;
  const int M = in_sizes[2] / D;
  const int MP = M + NLBL * 64;     // padded row cap (queries)
  const int NP = N + NLBL * 64;     // padded row cap (keys)
  const int TQCAP = (M + 63) / 64 + NLBL;
  const int TKCAP = (N + 63) / 64 + NLBL;

  // ---- workspace layout ----
  int* cnt = (int*)d_ws;            // 32
  int* off = cnt + 32;              // 32
  int* pqo = off + 32;              // 16
  int* pko = pqo + 16;              // 16
  int* ntl = pko + 16;              // 16
  int* tq  = ntl + 16;              // 2*TQCAP
  int* tk  = tq + 2 * TQCAP;        // 2*TKCAP
  int* korder = tk + 2 * TKCAP;     // N
  int* qorder = korder + N;         // M
  size_t ihdr = (((size_t)(112 + 2 * TQCAP + 2 * TKCAP + N + M)) * 4 + 255) & ~(size_t)255;

  __bf16* Wqt = (__bf16*)((char*)d_ws + ihdr);
  __bf16* Wkt = Wqt + (size_t)9 * 65536;
  __bf16* Wvt = Wkt + (size_t)9 * 65536;
  __bf16* Wft = Wvt + (size_t)9 * 65536;
  __bf16* cg  = Wft + 65536;                         // MP*D bf16
  float* qbuf = (float*)(cg + (size_t)MP * D);
  float* kbuf = qbuf + (size_t)MP * D;
  float* vbuf = kbuf + (size_t)NP * D;
  float* rbuf = vbuf + (size_t)NP * D;

  hipMemsetAsync(cnt, 0, 18 * sizeof(int), stream);
  count_kernel<<<(N + M + 255) / 256, 256, 0, stream>>>(lbl1, N, lbl2, M, cnt);
  offsets_kernel<<<1, 1, 0, stream>>>(cnt, off, pqo, pko, tq, tk, ntl);
  dim3 sgrid(NLBL, 2);
  scatter_kernel<<<sgrid, 256, 0, stream>>>(lbl1, N, lbl2, M, off, korder, qorder);

  transW_kernel<<<dim3(16, 28), 256, 0, stream>>>(Wq, Wk, Wv, Wf, Wqt, Wkt, Wvt, Wft);

  int gx = (TQCAP > TKCAP) ? TQCAP : TKCAP;
  gemm_in_kernel<<<dim3(gx, 3), 256, 0, stream>>>(
      query, key, value, Wqt, Wkt, Wvt, bq, bk, bv,
      qorder, korder, off, cnt, pqo, pko, tq, tk, ntl, qbuf, kbuf, vbuf);

  dim3 agrid((M + 63) / 64, H, NLBL);
  attn_kernel<<<agrid, 256, 0, stream>>>(qbuf, kbuf, vbuf, cnt, pqo, pko, cg);

  gemm_out_kernel<<<TQCAP, 256, 0, stream>>>(cg, Wft, bf_, tq, ntl, rbuf);

  ln_kernel<<<M + NLBL * 64, 256, 0, stream>>>(rbuf, query, qorder, off, cnt, pqo,
                                               gamma, beta, out);
}

// Round 4
// 192.956 us; speedup vs baseline: 26.9130x; 3.9443x over previous
//
#include <hip/hip_runtime.h>
#include <hip/hip_bf16.h>

#define D 256
#define H 4
#define DPH 64
#define NLBL 9

typedef __attribute__((ext_vector_type(8))) __bf16 bf16x8;
typedef __attribute__((ext_vector_type(4))) float f32x4;

__device__ __forceinline__ int sw_idx(int row, int col) {
  // ushort-unit index into a [64][64] bf16 LDS tile, XOR-swizzled so that
  // 16B fragment reads from 16 different rows spread across all banks.
  return row * 64 + (col ^ ((row & 7) << 3));
}

__device__ __forceinline__ unsigned int pk2(float a, float b) {
  unsigned int lo = (unsigned int)__builtin_bit_cast(unsigned short, (__bf16)a);
  unsigned int hi = (unsigned int)__builtin_bit_cast(unsigned short, (__bf16)b);
  return lo | (hi << 16);
}

__device__ __forceinline__ bf16x8 cvt8(float4 u0, float4 u1) {
  bf16x8 r;
  r[0] = (__bf16)u0.x; r[1] = (__bf16)u0.y; r[2] = (__bf16)u0.z; r[3] = (__bf16)u0.w;
  r[4] = (__bf16)u1.x; r[5] = (__bf16)u1.y; r[6] = (__bf16)u1.z; r[7] = (__bf16)u1.w;
  return r;
}

// ---------------------------------------------------------------------------
// Label bucketing: histogram -> offsets/padded offsets/tile tables -> scatter.
// ---------------------------------------------------------------------------
__global__ __launch_bounds__(256) void count_kernel(
    const int* __restrict__ lbl1, int n1, const int* __restrict__ lbl2, int n2,
    int* __restrict__ cnt) {
  int t = blockIdx.x * 256 + threadIdx.x;
  if (t < n1) atomicAdd(&cnt[lbl1[t]], 1);
  else if (t < n1 + n2) atomicAdd(&cnt[NLBL + lbl2[t - n1]], 1);
}

__global__ void offsets_kernel(const int* __restrict__ cnt, int* __restrict__ off,
                               int* __restrict__ pqo, int* __restrict__ pko,
                               int* __restrict__ tq, int* __restrict__ tk,
                               int* __restrict__ ntl) {
  if (threadIdx.x != 0) return;
  int a0 = 0, a1 = 0, p0 = 0, p1 = 0, t0 = 0, t1 = 0;
  for (int l = 0; l < NLBL; ++l) {
    off[l] = a0;      a0 += cnt[l];
    off[10 + l] = a1; a1 += cnt[NLBL + l];
    pko[l] = p0; pqo[l] = p1;
    int tkl = (cnt[l] + 63) >> 6, tql = (cnt[NLBL + l] + 63) >> 6;
    for (int i = 0; i < tkl; ++i) { tk[2 * t0] = l; tk[2 * t0 + 1] = p0 + (i << 6); ++t0; }
    for (int i = 0; i < tql; ++i) { tq[2 * t1] = l; tq[2 * t1 + 1] = p1 + (i << 6); ++t1; }
    p0 += tkl << 6; p1 += tql << 6;
  }
  off[9] = a0; off[19] = a1; pko[9] = p0; pqo[9] = p1;
  ntl[0] = t1; ntl[1] = t0;
}

__global__ __launch_bounds__(256) void scatter_kernel(
    const int* __restrict__ lbl1, int n1, const int* __restrict__ lbl2, int n2,
    const int* __restrict__ off, int* __restrict__ korder, int* __restrict__ qorder) {
  const int l = blockIdx.x;
  const int a = blockIdx.y;
  const int n = (a == 0) ? n1 : n2;
  const int* lbl = (a == 0) ? lbl1 : lbl2;
  int* order = (a == 0) ? korder : qorder;
  const int base = off[a * 10 + l];

  const int t = threadIdx.x, wave = t >> 6, lane = t & 63;
  __shared__ int wtot[4];
  int pos = 0;
  for (int chunk = 0; chunk < n; chunk += 256) {
    int i = chunk + t;
    bool flag = (i < n) && (lbl[i] == l);
    unsigned long long bal = __ballot(flag);
    int wprefix = __popcll(bal & ((1ull << lane) - 1ull));
    if (lane == 0) wtot[wave] = __popcll(bal);
    __syncthreads();
    int prew = 0;
#pragma unroll
    for (int w = 0; w < 4; ++w) prew += (w < wave) ? wtot[w] : 0;
    int tot = wtot[0] + wtot[1] + wtot[2] + wtot[3];
    if (flag) order[base + pos + prew + wprefix] = i;
    pos += tot;
    __syncthreads();
  }
}

// ---------------------------------------------------------------------------
// Transpose+cast weights: Wt[n][k] = bf16(W[k][n]).
// ---------------------------------------------------------------------------
__global__ __launch_bounds__(256) void transW_kernel(
    const float* __restrict__ Wq, const float* __restrict__ Wk,
    const float* __restrict__ Wv, const float* __restrict__ Wf,
    __bf16* __restrict__ Wqt, __bf16* __restrict__ Wkt,
    __bf16* __restrict__ Wvt, __bf16* __restrict__ Wft) {
  int m = blockIdx.y, sub = blockIdx.x;
  const float* src; __bf16* dst;
  if (m < 9)       { src = Wq + (size_t)m * 65536;        dst = Wqt + (size_t)m * 65536; }
  else if (m < 18) { src = Wk + (size_t)(m - 9) * 65536;  dst = Wkt + (size_t)(m - 9) * 65536; }
  else if (m < 27) { src = Wv + (size_t)(m - 18) * 65536; dst = Wvt + (size_t)(m - 18) * 65536; }
  else             { src = Wf;                            dst = Wft; }
  int k0 = (sub >> 2) << 6, n0 = (sub & 3) << 6;
  __shared__ float lds[64][65];
  int t = threadIdx.x, rr = t >> 6, c = t & 63;
#pragma unroll
  for (int i = 0; i < 16; ++i) {
    int r = i * 4 + rr;
    lds[r][c] = src[(size_t)(k0 + r) * D + n0 + c];
  }
  __syncthreads();
#pragma unroll
  for (int i = 0; i < 16; ++i) {
    int r = i * 4 + rr;
    dst[(size_t)(n0 + r) * D + k0 + c] = (__bf16)lds[c][r];
  }
}

// ---------------------------------------------------------------------------
// Label-routed input projections via MFMA bf16 (sorted-padded output rows).
// ---------------------------------------------------------------------------
__global__ __launch_bounds__(256) void gemm_in_kernel(
    const float* __restrict__ query, const float* __restrict__ key,
    const float* __restrict__ value,
    const __bf16* __restrict__ Wqt, const __bf16* __restrict__ Wkt,
    const __bf16* __restrict__ Wvt,
    const float* __restrict__ bq, const float* __restrict__ bk,
    const float* __restrict__ bv,
    const int* __restrict__ qorder, const int* __restrict__ korder,
    const int* __restrict__ off, const int* __restrict__ cnt,
    const int* __restrict__ pqo, const int* __restrict__ pko,
    const int* __restrict__ tq, const int* __restrict__ tk,
    const int* __restrict__ ntl,
    float* __restrict__ qbuf, float* __restrict__ kbuf, float* __restrict__ vbuf) {
  const int y = blockIdx.y;
  const int nt = (y == 0) ? ntl[0] : ntl[1];
  if ((int)blockIdx.x >= nt) return;
  const int* tt = (y == 0) ? tq : tk;
  const float* x = (y == 0) ? query : (y == 1 ? key : value);
  const __bf16* W = (y == 0) ? Wqt : (y == 1 ? Wkt : Wvt);
  const float* bias = (y == 0) ? bq : (y == 1 ? bk : bv);
  const int* order = (y == 0) ? qorder : korder;
  const int* po = (y == 0) ? pqo : pko;
  float* outp = (y == 0) ? qbuf : (y == 1 ? kbuf : vbuf);

  const int l = tt[2 * blockIdx.x], prow0 = tt[2 * blockIdx.x + 1];
  const int cl = (y == 0) ? cnt[NLBL + l] : cnt[l];
  const int ooff = (y == 0) ? off[10 + l] : off[l];
  const int base = prow0 - po[l];

  const int t = threadIdx.x, w = t >> 6, lane = t & 63;
  const int lr = lane & 15, lk = lane >> 4;

  int src[4];
#pragma unroll
  for (int fi = 0; fi < 4; ++fi) {
    int ridx = base + fi * 16 + lr;
    src[fi] = (ridx < cl) ? order[ooff + ridx] : -1;
  }

  bf16x8 az;
#pragma unroll
  for (int j = 0; j < 8; ++j) az[j] = (__bf16)0.f;

  f32x4 acc[4][4];
#pragma unroll
  for (int i = 0; i < 4; ++i)
#pragma unroll
    for (int j = 0; j < 4; ++j) acc[i][j] = (f32x4){0.f, 0.f, 0.f, 0.f};

  for (int kb = 0; kb < 8; ++kb) {
    const int kbase = kb * 32 + lk * 8;
    bf16x8 a[4], b[4];
#pragma unroll
    for (int fi = 0; fi < 4; ++fi) {
      if (src[fi] >= 0) {
        const float* ap = x + (size_t)src[fi] * D + kbase;
        float4 u0 = *(const float4*)ap;
        float4 u1 = *(const float4*)(ap + 4);
        a[fi] = cvt8(u0, u1);
      } else {
        a[fi] = az;
      }
    }
#pragma unroll
    for (int fj = 0; fj < 4; ++fj) {
      int col = w * 64 + fj * 16 + lr;
      b[fj] = *(const bf16x8*)(W + (size_t)l * 65536 + (size_t)col * D + kbase);
    }
#pragma unroll
    for (int fi = 0; fi < 4; ++fi)
#pragma unroll
      for (int fj = 0; fj < 4; ++fj)
        acc[fi][fj] = __builtin_amdgcn_mfma_f32_16x16x32_bf16(a[fi], b[fj], acc[fi][fj], 0, 0, 0);
  }

#pragma unroll
  for (int fj = 0; fj < 4; ++fj) {
    int col = w * 64 + fj * 16 + lr;
    float bv_ = bias[l * D + col];
#pragma unroll
    for (int fi = 0; fi < 4; ++fi)
#pragma unroll
      for (int r = 0; r < 4; ++r) {
        int row = prow0 + fi * 16 + lk * 4 + r;
        outp[(size_t)row * D + col] = acc[fi][fj][r] + bv_;
      }
  }
}

// ---------------------------------------------------------------------------
// MFMA flash attention over one (label, head, 64-query tile).
// 4 waves x 16 queries. S^T = mfma(K, Q) so query lives on lane&15; softmax
// stats via 2 shfl_xor. PV: O^T = mfma(V^T, P), P staged via per-wave LDS.
// All LDS tiles XOR-swizzled (row-stride 128B otherwise aliases all banks).
// ---------------------------------------------------------------------------
__global__ __launch_bounds__(256) void attn_mfma(
    const float* __restrict__ qbuf, const float* __restrict__ kbuf,
    const float* __restrict__ vbuf, const int* __restrict__ cnt,
    const int* __restrict__ pqo, const int* __restrict__ pko,
    __bf16* __restrict__ cg) {
  const int l = blockIdx.z, h = blockIdx.y;
  const int nq = cnt[NLBL + l], nk = cnt[l];
  const int qtile = blockIdx.x * 64;
  if (qtile >= nq) return;

  const int t = threadIdx.x;
  const int w = t >> 6, lane = t & 63;
  const int lr = lane & 15, lk = lane >> 4;

  __shared__ __align__(16) unsigned short ks[4096];   // K tile  [key][d]  bf16
  __shared__ __align__(16) unsigned short vst[4096];  // V tile  [d][key]  bf16
  __shared__ __align__(16) unsigned short plds[4096]; // P       [wave][q][key]

  // Q fragments (B operand), loaded once per block.
  const int qrow = pqo[l] + qtile + w * 16 + lr;
  bf16x8 b_q[2];
  {
    const float* qp = qbuf + (size_t)qrow * D + h * DPH + lk * 8;
#pragma unroll
    for (int kb = 0; kb < 2; ++kb) {
      float4 u0 = *(const float4*)(qp + kb * 32);
      float4 u1 = *(const float4*)(qp + kb * 32 + 4);
      b_q[kb] = cvt8(u0, u1);
    }
  }

  f32x4 acc_o[4];
#pragma unroll
  for (int i = 0; i < 4; ++i) acc_o[i] = (f32x4){0.f, 0.f, 0.f, 0.f};
  float mrun = -3.4e38f, lrun = 0.f;
  const int kb0 = pko[l];

  for (int n0 = 0; n0 < nk; n0 += 64) {
    __syncthreads();
    // ---- stage K tile: thread -> row=t>>2, 16 dims at (t&3)*16
    {
      int row = t >> 2, c0 = (t & 3) * 16;
      const float* kp = kbuf + (size_t)(kb0 + n0 + row) * D + h * DPH + c0;
      float4 a0 = *(const float4*)kp;
      float4 a1 = *(const float4*)(kp + 4);
      float4 a2 = *(const float4*)(kp + 8);
      float4 a3 = *(const float4*)(kp + 12);
      *(bf16x8*)&ks[sw_idx(row, c0)] = cvt8(a0, a1);
      *(bf16x8*)&ks[sw_idx(row, c0 + 8)] = cvt8(a2, a3);
    }
    // ---- stage V tile transposed: thread -> keys (t&31)*2,+1; dims (t>>5)*8
    {
      int key2 = (t & 31) * 2, d0 = (t >> 5) * 8;
      const float* v0p = vbuf + (size_t)(kb0 + n0 + key2) * D + h * DPH + d0;
      const float* v1p = v0p + D;
      float4 a0 = *(const float4*)v0p, a1 = *(const float4*)(v0p + 4);
      float4 b0 = *(const float4*)v1p, b1 = *(const float4*)(v1p + 4);
      float va[8] = {a0.x, a0.y, a0.z, a0.w, a1.x, a1.y, a1.z, a1.w};
      float vb[8] = {b0.x, b0.y, b0.z, b0.w, b1.x, b1.y, b1.z, b1.w};
#pragma unroll
      for (int i = 0; i < 8; ++i)
        *(unsigned int*)&vst[sw_idx(d0 + i, key2)] = pk2(va[i], vb[i]);
    }
    __syncthreads();

    // ---- S^T = K_tile x Q^T : C[key][q], key = fi*16 + lk*4 + r, q = lr
    f32x4 s_acc[4];
    const f32x4 zz = {0.f, 0.f, 0.f, 0.f};
#pragma unroll
    for (int fi = 0; fi < 4; ++fi) {
      bf16x8 a0 = *(const bf16x8*)&ks[sw_idx(fi * 16 + lr, lk * 8)];
      s_acc[fi] = __builtin_amdgcn_mfma_f32_16x16x32_bf16(a0, b_q[0], zz, 0, 0, 0);
    }
#pragma unroll
    for (int fi = 0; fi < 4; ++fi) {
      bf16x8 a1 = *(const bf16x8*)&ks[sw_idx(fi * 16 + lr, 32 + lk * 8)];
      s_acc[fi] = __builtin_amdgcn_mfma_f32_16x16x32_bf16(a1, b_q[1], s_acc[fi], 0, 0, 0);
    }

    // ---- online softmax (per query q=lr; reduce across lk groups)
    float p[16];
    float tm = -3.4e38f;
#pragma unroll
    for (int fi = 0; fi < 4; ++fi)
#pragma unroll
      for (int r = 0; r < 4; ++r) {
        int key = n0 + fi * 16 + lk * 4 + r;
        float v = s_acc[fi][r] * 0.25f;   // scale = (DPH//H)^-0.5
        v = (key < nk) ? v : -1e30f;
        p[fi * 4 + r] = v;
        tm = fmaxf(tm, v);
      }
    tm = fmaxf(tm, __shfl_xor(tm, 16, 64));
    tm = fmaxf(tm, __shfl_xor(tm, 32, 64));
    float mnew = fmaxf(mrun, tm);
    float alpha = __expf(mrun - mnew);
    lrun *= alpha;
#pragma unroll
    for (int fi = 0; fi < 4; ++fi) acc_o[fi] = acc_o[fi] * alpha;
    float ts = 0.f;
#pragma unroll
    for (int i = 0; i < 16; ++i) { p[i] = __expf(p[i] - mnew); ts += p[i]; }
    ts += __shfl_xor(ts, 16, 64);
    ts += __shfl_xor(ts, 32, 64);
    lrun += ts;
    mrun = mnew;

    // ---- P -> per-wave LDS (bf16, swizzled by q row)
#pragma unroll
    for (int fi = 0; fi < 4; ++fi) {
      unsigned int w0 = pk2(p[fi * 4 + 0], p[fi * 4 + 1]);
      unsigned int w1 = pk2(p[fi * 4 + 2], p[fi * 4 + 3]);
      int idx = w * 1024 + sw_idx(lr, fi * 16 + lk * 4);
      *(uint2*)&plds[idx] = make_uint2(w0, w1);
    }

    // ---- O^T += V^T x P : C[d][q], d = fi*16 + lk*4 + r
#pragma unroll
    for (int kb = 0; kb < 2; ++kb) {
      bf16x8 bp = *(const bf16x8*)&plds[w * 1024 + sw_idx(lr, kb * 32 + lk * 8)];
#pragma unroll
      for (int fi = 0; fi < 4; ++fi) {
        bf16x8 av = *(const bf16x8*)&vst[sw_idx(fi * 16 + lr, kb * 32 + lk * 8)];
        acc_o[fi] = __builtin_amdgcn_mfma_f32_16x16x32_bf16(av, bp, acc_o[fi], 0, 0, 0);
      }
    }
  }

  float inv = (lrun > 0.f) ? (1.f / lrun) : 0.f;
  __bf16* op = cg + (size_t)qrow * D + h * DPH;
#pragma unroll
  for (int fi = 0; fi < 4; ++fi) {
    unsigned int w0 = pk2(acc_o[fi][0] * inv, acc_o[fi][1] * inv);
    unsigned int w1 = pk2(acc_o[fi][2] * inv, acc_o[fi][3] * inv);
    *(uint2*)(op + fi * 16 + lk * 4) = make_uint2(w0, w1);
  }
}

// ---------------------------------------------------------------------------
// Output projection: rbuf = cg @ Wf + bf (sorted-padded rows). MFMA bf16.
// ---------------------------------------------------------------------------
__global__ __launch_bounds__(256) void gemm_out_kernel(
    const __bf16* __restrict__ cg, const __bf16* __restrict__ Wft,
    const float* __restrict__ bf_, const int* __restrict__ tq,
    const int* __restrict__ ntl, float* __restrict__ rbuf) {
  if ((int)blockIdx.x >= ntl[0]) return;
  const int prow0 = tq[2 * blockIdx.x + 1];
  const int t = threadIdx.x, w = t >> 6, lane = t & 63;
  const int lr = lane & 15, lk = lane >> 4;

  f32x4 acc[4][4];
#pragma unroll
  for (int i = 0; i < 4; ++i)
#pragma unroll
    for (int j = 0; j < 4; ++j) acc[i][j] = (f32x4){0.f, 0.f, 0.f, 0.f};

  for (int kb = 0; kb < 8; ++kb) {
    const int kbase = kb * 32 + lk * 8;
    bf16x8 a[4], b[4];
#pragma unroll
    for (int fi = 0; fi < 4; ++fi)
      a[fi] = *(const bf16x8*)(cg + (size_t)(prow0 + fi * 16 + lr) * D + kbase);
#pragma unroll
    for (int fj = 0; fj < 4; ++fj) {
      int col = w * 64 + fj * 16 + lr;
      b[fj] = *(const bf16x8*)(Wft + (size_t)col * D + kbase);
    }
#pragma unroll
    for (int fi = 0; fi < 4; ++fi)
#pragma unroll
      for (int fj = 0; fj < 4; ++fj)
        acc[fi][fj] = __builtin_amdgcn_mfma_f32_16x16x32_bf16(a[fi], b[fj], acc[fi][fj], 0, 0, 0);
  }

#pragma unroll
  for (int fj = 0; fj < 4; ++fj) {
    int col = w * 64 + fj * 16 + lr;
    float bv_ = bf_[col];
#pragma unroll
    for (int fi = 0; fi < 4; ++fi)
#pragma unroll
      for (int r = 0; r < 4; ++r) {
        int row = prow0 + fi * 16 + lk * 4 + r;
        rbuf[(size_t)row * D + col] = acc[fi][fj][r] + bv_;
      }
  }
}

// ---------------------------------------------------------------------------
// res = rbuf + query[src]; LayerNorm; scatter to out[src].
// ---------------------------------------------------------------------------
__device__ inline float wave_sum(float v) {
#pragma unroll
  for (int off = 32; off > 0; off >>= 1) v += __shfl_down(v, off, 64);
  return v;
}

__global__ __launch_bounds__(256) void ln_kernel(
    const float* __restrict__ rbuf, const float* __restrict__ query,
    const int* __restrict__ qorder, const int* __restrict__ off,
    const int* __restrict__ cnt, const int* __restrict__ pqo,
    const float* __restrict__ gamma, const float* __restrict__ beta,
    float* __restrict__ out) {
  int row = blockIdx.x;
  if (row >= pqo[9]) return;
  int l = 0;
#pragma unroll
  for (int i = 0; i < 8; ++i)
    if (row >= pqo[i + 1]) l = i + 1;
  int idx = row - pqo[l];
  if (idx >= cnt[NLBL + l]) return;
  int src = qorder[off[10 + l] + idx];

  int o = threadIdx.x;
  __shared__ float red[8];
  float res = rbuf[(size_t)row * D + o] + query[(size_t)src * D + o];

  int wid = o >> 6, lane = o & 63;
  float s = wave_sum(res);
  if (lane == 0) red[wid] = s;
  __syncthreads();
  float mu = (red[0] + red[1] + red[2] + red[3]) * (1.f / D);
  float dv = (res - mu) * (res - mu);
  float s2 = wave_sum(dv);
  if (lane == 0) red[4 + wid] = s2;
  __syncthreads();
  float var = (red[4] + red[5] + red[6] + red[7]) * (1.f / D);
  out[(size_t)src * D + o] = (res - mu) * rsqrtf(var + 1e-5f) * gamma[o] + beta[o];
}

// ---------------------------------------------------------------------------
extern "C" void kernel_launch(void* const* d_in, const int* in_sizes, int n_in,
                              void* d_out, int out_size, void* d_ws, size_t ws_size,
                              hipStream_t stream) {
  const float* key   = (const float*)d_in[0];
  const float* value = (const float*)d_in[1];
  const float* query = (const float*)d_in[2];
  const int*   lbl1  = (const int*)d_in[3];
  const int*   lbl2  = (const int*)d_in[4];
  const float* Wq = (const float*)d_in[5];
  const float* bq = (const float*)d_in[6];
  const float* Wk = (const float*)d_in[7];
  const float* bk = (const float*)d_in[8];
  const float* Wv = (const float*)d_in[9];
  const float* bv = (const float*)d_in[10];
  const float* Wf = (const float*)d_in[11];
  const float* bf_ = (const float*)d_in[12];
  const float* gamma = (const float*)d_in[13];
  const float* beta  = (const float*)d_in[14];
  float* out = (float*)d_out;

  const int N = in_sizes[0] / D;
  const int M = in_sizes[2] / D;
  const int MP = M + NLBL * 64;
  const int NP = N + NLBL * 64;
  const int TQCAP = (M + 63) / 64 + NLBL;
  const int TKCAP = (N + 63) / 64 + NLBL;

  int* cnt = (int*)d_ws;
  int* off = cnt + 32;
  int* pqo = off + 32;
  int* pko = pqo + 16;
  int* ntl = pko + 16;
  int* tq  = ntl + 16;
  int* tk  = tq + 2 * TQCAP;
  int* korder = tk + 2 * TKCAP;
  int* qorder = korder + N;
  size_t ihdr = (((size_t)(112 + 2 * TQCAP + 2 * TKCAP + N + M)) * 4 + 255) & ~(size_t)255;

  __bf16* Wqt = (__bf16*)((char*)d_ws + ihdr);
  __bf16* Wkt = Wqt + (size_t)9 * 65536;
  __bf16* Wvt = Wkt + (size_t)9 * 65536;
  __bf16* Wft = Wvt + (size_t)9 * 65536;
  __bf16* cg  = Wft + 65536;
  float* qbuf = (float*)(cg + (size_t)MP * D);
  float* kbuf = qbuf + (size_t)MP * D;
  float* vbuf = kbuf + (size_t)NP * D;
  float* rbuf = vbuf + (size_t)NP * D;

  hipMemsetAsync(cnt, 0, 18 * sizeof(int), stream);
  count_kernel<<<(N + M + 255) / 256, 256, 0, stream>>>(lbl1, N, lbl2, M, cnt);
  offsets_kernel<<<1, 1, 0, stream>>>(cnt, off, pqo, pko, tq, tk, ntl);
  dim3 sgrid(NLBL, 2);
  scatter_kernel<<<sgrid, 256, 0, stream>>>(lbl1, N, lbl2, M, off, korder, qorder);

  transW_kernel<<<dim3(16, 28), 256, 0, stream>>>(Wq, Wk, Wv, Wf, Wqt, Wkt, Wvt, Wft);

  int gx = (TQCAP > TKCAP) ? TQCAP : TKCAP;
  gemm_in_kernel<<<dim3(gx, 3), 256, 0, stream>>>(
      query, key, value, Wqt, Wkt, Wvt, bq, bk, bv,
      qorder, korder, off, cnt, pqo, pko, tq, tk, ntl, qbuf, kbuf, vbuf);

  dim3 agrid((M + 63) / 64, H, NLBL);
  attn_mfma<<<agrid, 256, 0, stream>>>(qbuf, kbuf, vbuf, cnt, pqo, pko, cg);

  gemm_out_kernel<<<TQCAP, 256, 0, stream>>>(cg, Wft, bf_, tq, ntl, rbuf);

  ln_kernel<<<M + NLBL * 64, 256, 0, stream>>>(rbuf, query, qorder, off, cnt, pqo,
                                               gamma, beta, out);
}

// Round 5
// 150.243 us; speedup vs baseline: 34.5644x; 1.2843x over previous
//
#include <hip/hip_runtime.h>
#include <hip/hip_bf16.h>

#define D 256
#define H 4
#define DPH 64
#define NLBL 9
#define SPLITK 4

typedef __attribute__((ext_vector_type(8))) __bf16 bf16x8;
typedef __attribute__((ext_vector_type(8))) unsigned short u16x8;
typedef __attribute__((ext_vector_type(4))) float f32x4;

__device__ __forceinline__ int sw_idx(int row, int col) {
  // ushort-unit index into a [64][64] bf16 LDS tile, XOR-swizzled.
  return row * 64 + (col ^ ((row & 7) << 3));
}

__device__ __forceinline__ unsigned int pk2(float a, float b) {
  unsigned int lo = (unsigned int)__builtin_bit_cast(unsigned short, (__bf16)a);
  unsigned int hi = (unsigned int)__builtin_bit_cast(unsigned short, (__bf16)b);
  return lo | (hi << 16);
}

__device__ __forceinline__ bf16x8 cvt8(float4 u0, float4 u1) {
  bf16x8 r;
  r[0] = (__bf16)u0.x; r[1] = (__bf16)u0.y; r[2] = (__bf16)u0.z; r[3] = (__bf16)u0.w;
  r[4] = (__bf16)u1.x; r[5] = (__bf16)u1.y; r[6] = (__bf16)u1.z; r[7] = (__bf16)u1.w;
  return r;
}

// ---------------------------------------------------------------------------
// Label bucketing.
// ---------------------------------------------------------------------------
__global__ __launch_bounds__(256) void count_kernel(
    const int* __restrict__ lbl1, int n1, const int* __restrict__ lbl2, int n2,
    int* __restrict__ cnt) {
  int t = blockIdx.x * 256 + threadIdx.x;
  if (t < n1) atomicAdd(&cnt[lbl1[t]], 1);
  else if (t < n1 + n2) atomicAdd(&cnt[NLBL + lbl2[t - n1]], 1);
}

__global__ void offsets_kernel(const int* __restrict__ cnt, int* __restrict__ off,
                               int* __restrict__ pqo, int* __restrict__ pko,
                               int* __restrict__ tq, int* __restrict__ tk,
                               int* __restrict__ ntl) {
  if (threadIdx.x != 0) return;
  int a0 = 0, a1 = 0, p0 = 0, p1 = 0, t0 = 0, t1 = 0;
  for (int l = 0; l < NLBL; ++l) {
    off[l] = a0;      a0 += cnt[l];
    off[10 + l] = a1; a1 += cnt[NLBL + l];
    pko[l] = p0; pqo[l] = p1;
    int tkl = (cnt[l] + 63) >> 6, tql = (cnt[NLBL + l] + 63) >> 6;
    for (int i = 0; i < tkl; ++i) { tk[2 * t0] = l; tk[2 * t0 + 1] = p0 + (i << 6); ++t0; }
    for (int i = 0; i < tql; ++i) { tq[2 * t1] = l; tq[2 * t1 + 1] = p1 + (i << 6); ++t1; }
    p0 += tkl << 6; p1 += tql << 6;
  }
  off[9] = a0; off[19] = a1; pko[9] = p0; pqo[9] = p1;
  ntl[0] = t1; ntl[1] = t0;
}

__global__ __launch_bounds__(1024) void scatter_kernel(
    const int* __restrict__ lbl1, int n1, const int* __restrict__ lbl2, int n2,
    const int* __restrict__ off, int* __restrict__ korder, int* __restrict__ qorder) {
  const int l = blockIdx.x;
  const int a = blockIdx.y;
  const int n = (a == 0) ? n1 : n2;
  const int* lbl = (a == 0) ? lbl1 : lbl2;
  int* order = (a == 0) ? korder : qorder;
  const int base = off[a * 10 + l];

  const int t = threadIdx.x, wave = t >> 6, lane = t & 63;
  __shared__ int wtot[16];
  int pos = 0;
  for (int chunk = 0; chunk < n; chunk += 1024) {
    int i = chunk + t;
    bool flag = (i < n) && (lbl[i] == l);
    unsigned long long bal = __ballot(flag);
    int wprefix = __popcll(bal & ((1ull << lane) - 1ull));
    if (lane == 0) wtot[wave] = __popcll(bal);
    __syncthreads();
    int prew = 0, tot = 0;
#pragma unroll
    for (int w = 0; w < 16; ++w) {
      prew += (w < wave) ? wtot[w] : 0;
      tot += wtot[w];
    }
    if (flag) order[base + pos + prew + wprefix] = i;
    pos += tot;
    __syncthreads();
  }
}

// ---------------------------------------------------------------------------
// Transpose+cast weights: Wt[n][k] = bf16(W[k][n]).
// ---------------------------------------------------------------------------
__global__ __launch_bounds__(256) void transW_kernel(
    const float* __restrict__ Wq, const float* __restrict__ Wk,
    const float* __restrict__ Wv, const float* __restrict__ Wf,
    __bf16* __restrict__ Wqt, __bf16* __restrict__ Wkt,
    __bf16* __restrict__ Wvt, __bf16* __restrict__ Wft) {
  int m = blockIdx.y, sub = blockIdx.x;
  const float* src; __bf16* dst;
  if (m < 9)       { src = Wq + (size_t)m * 65536;        dst = Wqt + (size_t)m * 65536; }
  else if (m < 18) { src = Wk + (size_t)(m - 9) * 65536;  dst = Wkt + (size_t)(m - 9) * 65536; }
  else if (m < 27) { src = Wv + (size_t)(m - 18) * 65536; dst = Wvt + (size_t)(m - 18) * 65536; }
  else             { src = Wf;                            dst = Wft; }
  int k0 = (sub >> 2) << 6, n0 = (sub & 3) << 6;
  __shared__ float lds[64][65];
  int t = threadIdx.x, rr = t >> 6, c = t & 63;
#pragma unroll
  for (int i = 0; i < 16; ++i) {
    int r = i * 4 + rr;
    lds[r][c] = src[(size_t)(k0 + r) * D + n0 + c];
  }
  __syncthreads();
#pragma unroll
  for (int i = 0; i < 16; ++i) {
    int r = i * 4 + rr;
    dst[(size_t)(n0 + r) * D + k0 + c] = (__bf16)lds[c][r];
  }
}

// ---------------------------------------------------------------------------
// Label-routed input projections via MFMA bf16 -> bf16 sorted-padded buffers.
// Query branch pre-scales by 0.25*log2(e) so attention uses exp2 directly.
// ---------------------------------------------------------------------------
__global__ __launch_bounds__(256) void gemm_in_kernel(
    const float* __restrict__ query, const float* __restrict__ key,
    const float* __restrict__ value,
    const __bf16* __restrict__ Wqt, const __bf16* __restrict__ Wkt,
    const __bf16* __restrict__ Wvt,
    const float* __restrict__ bq, const float* __restrict__ bk,
    const float* __restrict__ bv,
    const int* __restrict__ qorder, const int* __restrict__ korder,
    const int* __restrict__ off, const int* __restrict__ cnt,
    const int* __restrict__ pqo, const int* __restrict__ pko,
    const int* __restrict__ tq, const int* __restrict__ tk,
    const int* __restrict__ ntl,
    __bf16* __restrict__ qbuf, __bf16* __restrict__ kbuf, __bf16* __restrict__ vbuf) {
  const int y = blockIdx.y;
  const int nt = (y == 0) ? ntl[0] : ntl[1];
  if ((int)blockIdx.x >= nt) return;
  const int* tt = (y == 0) ? tq : tk;
  const float* x = (y == 0) ? query : (y == 1 ? key : value);
  const __bf16* W = (y == 0) ? Wqt : (y == 1 ? Wkt : Wvt);
  const float* bias = (y == 0) ? bq : (y == 1 ? bk : bv);
  const int* order = (y == 0) ? qorder : korder;
  const int* po = (y == 0) ? pqo : pko;
  __bf16* outp = (y == 0) ? qbuf : (y == 1 ? kbuf : vbuf);
  const float sc = (y == 0) ? 0.36067376f : 1.0f;   // 0.25 * log2(e)

  const int l = tt[2 * blockIdx.x], prow0 = tt[2 * blockIdx.x + 1];
  const int cl = (y == 0) ? cnt[NLBL + l] : cnt[l];
  const int ooff = (y == 0) ? off[10 + l] : off[l];
  const int base = prow0 - po[l];

  const int t = threadIdx.x, w = t >> 6, lane = t & 63;
  const int lr = lane & 15, lk = lane >> 4;

  int src[4];
#pragma unroll
  for (int fi = 0; fi < 4; ++fi) {
    int ridx = base + fi * 16 + lr;
    src[fi] = (ridx < cl) ? order[ooff + ridx] : -1;
  }

  bf16x8 az;
#pragma unroll
  for (int j = 0; j < 8; ++j) az[j] = (__bf16)0.f;

  f32x4 acc[4][4];
#pragma unroll
  for (int i = 0; i < 4; ++i)
#pragma unroll
    for (int j = 0; j < 4; ++j) acc[i][j] = (f32x4){0.f, 0.f, 0.f, 0.f};

  for (int kb = 0; kb < 8; ++kb) {
    const int kbase = kb * 32 + lk * 8;
    bf16x8 a[4], b[4];
#pragma unroll
    for (int fi = 0; fi < 4; ++fi) {
      if (src[fi] >= 0) {
        const float* ap = x + (size_t)src[fi] * D + kbase;
        float4 u0 = *(const float4*)ap;
        float4 u1 = *(const float4*)(ap + 4);
        a[fi] = cvt8(u0, u1);
      } else {
        a[fi] = az;
      }
    }
#pragma unroll
    for (int fj = 0; fj < 4; ++fj) {
      int col = w * 64 + fj * 16 + lr;
      b[fj] = *(const bf16x8*)(W + (size_t)l * 65536 + (size_t)col * D + kbase);
    }
#pragma unroll
    for (int fi = 0; fi < 4; ++fi)
#pragma unroll
      for (int fj = 0; fj < 4; ++fj)
        acc[fi][fj] = __builtin_amdgcn_mfma_f32_16x16x32_bf16(a[fi], b[fj], acc[fi][fj], 0, 0, 0);
  }

#pragma unroll
  for (int fj = 0; fj < 4; ++fj) {
    int col = w * 64 + fj * 16 + lr;
    float bv_ = bias[l * D + col];
#pragma unroll
    for (int fi = 0; fi < 4; ++fi)
#pragma unroll
      for (int r = 0; r < 4; ++r) {
        int row = prow0 + fi * 16 + lk * 4 + r;
        outp[(size_t)row * D + col] = (__bf16)((acc[fi][fj][r] + bv_) * sc);
      }
  }
}

// ---------------------------------------------------------------------------
// Split-K MFMA flash attention. grid=(TQCAP, H, SPLITK); tile-table driven.
// Writes unnormalized partials (fp32 ctx + m,l in exp2 domain) to ws.
// ---------------------------------------------------------------------------
__global__ __launch_bounds__(256) void attn_mfma(
    const __bf16* __restrict__ qbuf, const __bf16* __restrict__ kbuf,
    const __bf16* __restrict__ vbuf, const int* __restrict__ cnt,
    const int* __restrict__ tq, const int* __restrict__ ntl,
    const int* __restrict__ pko,
    float* __restrict__ pctx, float* __restrict__ pstats) {
  const int tqi = blockIdx.x;
  if (tqi >= ntl[0]) return;
  const int l = tq[2 * tqi], prow0 = tq[2 * tqi + 1];
  const int h = blockIdx.y, s = blockIdx.z;
  const int nk = cnt[l];
  const int ntiles = (nk + 63) >> 6;
  const int ntsz = (ntiles + SPLITK - 1) / SPLITK;
  const int tt0 = s * ntsz;
  const int tt1 = min(ntiles, tt0 + ntsz);
  if (tt0 >= tt1) return;

  const int t = threadIdx.x;
  const int w = t >> 6, lane = t & 63;
  const int lr = lane & 15, lk = lane >> 4;

  __shared__ __align__(16) unsigned short ks[4096];    // K tile [key][d]
  __shared__ __align__(16) unsigned short vtl[4096];   // V tile [d][key]
  __shared__ __align__(16) unsigned short plds[4096];  // P [wave][q][key]

  const int qloc = w * 16 + lr;
  const int qrow = prow0 + qloc;
  bf16x8 b_q[2];
#pragma unroll
  for (int kb = 0; kb < 2; ++kb)
    b_q[kb] = *(const bf16x8*)(qbuf + (size_t)qrow * D + h * DPH + kb * 32 + lk * 8);

  f32x4 acc_o[4];
#pragma unroll
  for (int i = 0; i < 4; ++i) acc_o[i] = (f32x4){0.f, 0.f, 0.f, 0.f};
  float mrun = -3.4e38f, lrun = 0.f;
  const int kb0 = pko[l];

  for (int tt = tt0; tt < tt1; ++tt) {
    const int n0 = tt << 6;
    __syncthreads();
    // ---- stage K tile (bf16 -> swizzled LDS), 32B per thread
    {
      int row = t >> 2, c0 = (t & 3) * 16;
      const uint4* kp = (const uint4*)(kbuf + (size_t)(kb0 + n0 + row) * D + h * DPH + c0);
      uint4 k0 = kp[0], k1 = kp[1];
      *(uint4*)&ks[sw_idx(row, c0)] = k0;
      *(uint4*)&ks[sw_idx(row, c0 + 8)] = k1;
    }
    // ---- stage V tile transposed (pack key pairs into u32)
    {
      int key2 = (t & 31) * 2, d0 = (t >> 5) * 8;
      const unsigned short* vp = (const unsigned short*)(vbuf + (size_t)(kb0 + n0 + key2) * D + h * DPH + d0);
      u16x8 va = *(const u16x8*)vp;
      u16x8 vb = *(const u16x8*)(vp + D);
#pragma unroll
      for (int j = 0; j < 8; ++j) {
        unsigned int u = (unsigned int)va[j] | ((unsigned int)vb[j] << 16);
        *(unsigned int*)&vtl[sw_idx(d0 + j, key2)] = u;
      }
    }
    __syncthreads();

    // ---- S^T = K x Q^T : C[key][q], key = fi*16 + lk*4 + r, q = lr
    f32x4 s_acc[4];
    const f32x4 zz = {0.f, 0.f, 0.f, 0.f};
#pragma unroll
    for (int fi = 0; fi < 4; ++fi) {
      bf16x8 a0 = *(const bf16x8*)&ks[sw_idx(fi * 16 + lr, lk * 8)];
      s_acc[fi] = __builtin_amdgcn_mfma_f32_16x16x32_bf16(a0, b_q[0], zz, 0, 0, 0);
    }
#pragma unroll
    for (int fi = 0; fi < 4; ++fi) {
      bf16x8 a1 = *(const bf16x8*)&ks[sw_idx(fi * 16 + lr, 32 + lk * 8)];
      s_acc[fi] = __builtin_amdgcn_mfma_f32_16x16x32_bf16(a1, b_q[1], s_acc[fi], 0, 0, 0);
    }

    // ---- online softmax in exp2 domain (logits pre-scaled in qbuf)
    float p[16];
    float tm = -3.4e38f;
#pragma unroll
    for (int fi = 0; fi < 4; ++fi)
#pragma unroll
      for (int r = 0; r < 4; ++r) {
        int key = n0 + fi * 16 + lk * 4 + r;
        float v = (key < nk) ? s_acc[fi][r] : -1e30f;
        p[fi * 4 + r] = v;
        tm = fmaxf(tm, v);
      }
    tm = fmaxf(tm, __shfl_xor(tm, 16, 64));
    tm = fmaxf(tm, __shfl_xor(tm, 32, 64));
    float mnew = fmaxf(mrun, tm);
    float alpha = exp2f(mrun - mnew);
    lrun *= alpha;
#pragma unroll
    for (int fi = 0; fi < 4; ++fi) acc_o[fi] = acc_o[fi] * alpha;
    float ts = 0.f;
#pragma unroll
    for (int i = 0; i < 16; ++i) { p[i] = exp2f(p[i] - mnew); ts += p[i]; }
    ts += __shfl_xor(ts, 16, 64);
    ts += __shfl_xor(ts, 32, 64);
    lrun += ts;
    mrun = mnew;

    // ---- P -> per-wave LDS
#pragma unroll
    for (int fi = 0; fi < 4; ++fi) {
      unsigned int w0 = pk2(p[fi * 4 + 0], p[fi * 4 + 1]);
      unsigned int w1 = pk2(p[fi * 4 + 2], p[fi * 4 + 3]);
      int idx = w * 1024 + sw_idx(lr, fi * 16 + lk * 4);
      *(uint2*)&plds[idx] = make_uint2(w0, w1);
    }

    // ---- O^T += V^T x P : C[d][q], d = fi*16 + lk*4 + r
#pragma unroll
    for (int kb = 0; kb < 2; ++kb) {
      bf16x8 bp = *(const bf16x8*)&plds[w * 1024 + sw_idx(lr, kb * 32 + lk * 8)];
#pragma unroll
      for (int fi = 0; fi < 4; ++fi) {
        bf16x8 av = *(const bf16x8*)&vtl[sw_idx(fi * 16 + lr, kb * 32 + lk * 8)];
        acc_o[fi] = __builtin_amdgcn_mfma_f32_16x16x32_bf16(av, bp, acc_o[fi], 0, 0, 0);
      }
    }
  }

  // ---- write partials
  const size_t base = ((size_t)tqi * H + h) * SPLITK + s;
  float* pc = pctx + base * 4096;
#pragma unroll
  for (int fi = 0; fi < 4; ++fi)
    *(f32x4*)(pc + qloc * 64 + fi * 16 + lk * 4) = acc_o[fi];
  if (lk == 0) {
    pstats[base * 128 + qloc * 2] = mrun;
    pstats[base * 128 + qloc * 2 + 1] = lrun;
  }
}

// ---------------------------------------------------------------------------
// Merge split-K partials, normalize, write cg (bf16). grid=(TQCAP, H).
// ---------------------------------------------------------------------------
__global__ __launch_bounds__(256) void attn_reduce(
    const float* __restrict__ pctx, const float* __restrict__ pstats,
    const int* __restrict__ cnt, const int* __restrict__ tq,
    const int* __restrict__ ntl, __bf16* __restrict__ cg) {
  const int tqi = blockIdx.x;
  if (tqi >= ntl[0]) return;
  const int l = tq[2 * tqi], prow0 = tq[2 * tqi + 1];
  const int h = blockIdx.y;
  const int t = threadIdx.x;
  const int q = t >> 2, part = t & 3;

  __bf16* op = cg + (size_t)(prow0 + q) * D + h * DPH + part * 16;

  const int nk = cnt[l];
  const int ntiles = (nk + 63) >> 6;
  float o[16];
#pragma unroll
  for (int j = 0; j < 16; ++j) o[j] = 0.f;

  if (ntiles > 0) {
    const int ntsz = (ntiles + SPLITK - 1) / SPLITK;
    const int nsp = (ntiles + ntsz - 1) / ntsz;
    const size_t base0 = ((size_t)tqi * H + h) * SPLITK;

    float m = -3.4e38f;
    for (int s = 0; s < nsp; ++s)
      m = fmaxf(m, pstats[(base0 + s) * 128 + q * 2]);
    float L = 0.f;
    float wgt[SPLITK];
    for (int s = 0; s < nsp; ++s) {
      float ms = pstats[(base0 + s) * 128 + q * 2];
      float ls = pstats[(base0 + s) * 128 + q * 2 + 1];
      wgt[s] = exp2f(ms - m);
      L += ls * wgt[s];
    }
    float inv = (L > 0.f) ? (1.f / L) : 0.f;
    for (int s = 0; s < nsp; ++s) {
      const float* pc = pctx + (base0 + s) * 4096 + q * 64 + part * 16;
      float wg = wgt[s] * inv;
#pragma unroll
      for (int j = 0; j < 16; ++j) o[j] += pc[j] * wg;
    }
  }

  uint4 o0, o1;
  o0.x = pk2(o[0], o[1]);  o0.y = pk2(o[2], o[3]);
  o0.z = pk2(o[4], o[5]);  o0.w = pk2(o[6], o[7]);
  o1.x = pk2(o[8], o[9]);  o1.y = pk2(o[10], o[11]);
  o1.z = pk2(o[12], o[13]); o1.w = pk2(o[14], o[15]);
  *(uint4*)op = o0;
  *(uint4*)(op + 8) = o1;
}

// ---------------------------------------------------------------------------
// Fused: rbuf = cg @ Wf + bf + query residual -> LayerNorm -> scatter to out.
// grid=(TQCAP, 2), 32 rows per block.
// ---------------------------------------------------------------------------
__global__ __launch_bounds__(256) void proj_ln_kernel(
    const __bf16* __restrict__ cg, const __bf16* __restrict__ Wft,
    const float* __restrict__ bf_, const float* __restrict__ query,
    const int* __restrict__ qorder, const int* __restrict__ off,
    const int* __restrict__ cnt, const int* __restrict__ pqo,
    const int* __restrict__ tq, const int* __restrict__ ntl,
    const float* __restrict__ gamma, const float* __restrict__ beta,
    float* __restrict__ out) {
  const int tqi = blockIdx.x;
  if (tqi >= ntl[0]) return;
  const int l = tq[2 * tqi];
  const int prow0 = tq[2 * tqi + 1] + blockIdx.y * 32;
  const int cl = cnt[NLBL + l];
  const int ooff = off[10 + l];
  const int base = prow0 - pqo[l];

  const int t = threadIdx.x, w = t >> 6, lane = t & 63;
  const int lr = lane & 15, lk = lane >> 4;

  __shared__ int srcs[32];
  __shared__ float psum[4][32], psum2[4][32];
  __shared__ float mu_s[32], is_s[32];

  if (t < 32) {
    int ridx = base + t;
    srcs[t] = (ridx < cl) ? qorder[ooff + ridx] : -1;
  }

  f32x4 acc[2][4];
#pragma unroll
  for (int i = 0; i < 2; ++i)
#pragma unroll
    for (int j = 0; j < 4; ++j) acc[i][j] = (f32x4){0.f, 0.f, 0.f, 0.f};

  for (int kb = 0; kb < 8; ++kb) {
    const int kbase = kb * 32 + lk * 8;
    bf16x8 a[2], b[4];
#pragma unroll
    for (int fi = 0; fi < 2; ++fi)
      a[fi] = *(const bf16x8*)(cg + (size_t)(prow0 + fi * 16 + lr) * D + kbase);
#pragma unroll
    for (int fj = 0; fj < 4; ++fj) {
      int col = w * 64 + fj * 16 + lr;
      b[fj] = *(const bf16x8*)(Wft + (size_t)col * D + kbase);
    }
#pragma unroll
    for (int fi = 0; fi < 2; ++fi)
#pragma unroll
      for (int fj = 0; fj < 4; ++fj)
        acc[fi][fj] = __builtin_amdgcn_mfma_f32_16x16x32_bf16(a[fi], b[fj], acc[fi][fj], 0, 0, 0);
  }

  __syncthreads();  // srcs ready

  float res[2][4][4];
  float s1[2][4], s2[2][4];
#pragma unroll
  for (int fi = 0; fi < 2; ++fi)
#pragma unroll
    for (int r = 0; r < 4; ++r) { s1[fi][r] = 0.f; s2[fi][r] = 0.f; }

#pragma unroll
  for (int fj = 0; fj < 4; ++fj) {
    int col = w * 64 + fj * 16 + lr;
    float bcol = bf_[col];
#pragma unroll
    for (int fi = 0; fi < 2; ++fi)
#pragma unroll
      for (int r = 0; r < 4; ++r) {
        int rowl = fi * 16 + lk * 4 + r;
        int sr = srcs[rowl];
        float qv = (sr >= 0) ? query[(size_t)sr * D + col] : 0.f;
        float v = acc[fi][fj][r] + bcol + qv;
        res[fi][fj][r] = v;
        s1[fi][r] += v;
        s2[fi][r] += v * v;
      }
  }

#pragma unroll
  for (int o2 = 1; o2 <= 8; o2 <<= 1) {
#pragma unroll
    for (int fi = 0; fi < 2; ++fi)
#pragma unroll
      for (int r = 0; r < 4; ++r) {
        s1[fi][r] += __shfl_xor(s1[fi][r], o2, 64);
        s2[fi][r] += __shfl_xor(s2[fi][r], o2, 64);
      }
  }
  if (lr == 0) {
#pragma unroll
    for (int fi = 0; fi < 2; ++fi)
#pragma unroll
      for (int r = 0; r < 4; ++r) {
        int rowl = fi * 16 + lk * 4 + r;
        psum[w][rowl] = s1[fi][r];
        psum2[w][rowl] = s2[fi][r];
      }
  }
  __syncthreads();
  if (t < 32) {
    float tot = psum[0][t] + psum[1][t] + psum[2][t] + psum[3][t];
    float tot2 = psum2[0][t] + psum2[1][t] + psum2[2][t] + psum2[3][t];
    float mu = tot * (1.f / D);
    float var = tot2 * (1.f / D) - mu * mu;
    mu_s[t] = mu;
    is_s[t] = rsqrtf(var + 1e-5f);
  }
  __syncthreads();

#pragma unroll
  for (int fj = 0; fj < 4; ++fj) {
    int col = w * 64 + fj * 16 + lr;
    float gc = gamma[col], bc = beta[col];
#pragma unroll
    for (int fi = 0; fi < 2; ++fi)
#pragma unroll
      for (int r = 0; r < 4; ++r) {
        int rowl = fi * 16 + lk * 4 + r;
        int sr = srcs[rowl];
        if (sr >= 0)
          out[(size_t)sr * D + col] =
              (res[fi][fj][r] - mu_s[rowl]) * is_s[rowl] * gc + bc;
      }
  }
}

// ---------------------------------------------------------------------------
extern "C" void kernel_launch(void* const* d_in, const int* in_sizes, int n_in,
                              void* d_out, int out_size, void* d_ws, size_t ws_size,
                              hipStream_t stream) {
  const float* key   = (const float*)d_in[0];
  const float* value = (const float*)d_in[1];
  const float* query = (const float*)d_in[2];
  const int*   lbl1  = (const int*)d_in[3];
  const int*   lbl2  = (const int*)d_in[4];
  const float* Wq = (const float*)d_in[5];
  const float* bq = (const float*)d_in[6];
  const float* Wk = (const float*)d_in[7];
  const float* bk = (const float*)d_in[8];
  const float* Wv = (const float*)d_in[9];
  const float* bv = (const float*)d_in[10];
  const float* Wf = (const float*)d_in[11];
  const float* bf_ = (const float*)d_in[12];
  const float* gamma = (const float*)d_in[13];
  const float* beta  = (const float*)d_in[14];
  float* out = (float*)d_out;

  const int N = in_sizes[0] / D;
  const int M = in_sizes[2] / D;
  const int MP = M + NLBL * 64;
  const int NP = N + NLBL * 64;
  const int TQCAP = (M + 63) / 64 + NLBL;
  const int TKCAP = (N + 63) / 64 + NLBL;

  int* cnt = (int*)d_ws;
  int* off = cnt + 32;
  int* pqo = off + 32;
  int* pko = pqo + 16;
  int* ntl = pko + 16;
  int* tq  = ntl + 16;
  int* tk  = tq + 2 * TQCAP;
  int* korder = tk + 2 * TKCAP;
  int* qorder = korder + N;
  size_t ihdr = (((size_t)(112 + 2 * TQCAP + 2 * TKCAP + N + M)) * 4 + 255) & ~(size_t)255;

  __bf16* Wqt = (__bf16*)((char*)d_ws + ihdr);
  __bf16* Wkt = Wqt + (size_t)9 * 65536;
  __bf16* Wvt = Wkt + (size_t)9 * 65536;
  __bf16* Wft = Wvt + (size_t)9 * 65536;
  __bf16* cg  = Wft + 65536;                       // MP*D
  __bf16* qbuf = cg + (size_t)MP * D;
  __bf16* kbuf = qbuf + (size_t)MP * D;
  __bf16* vbuf = kbuf + (size_t)NP * D;
  float* pctx = (float*)(vbuf + (size_t)NP * D);   // TQCAP*H*SPLITK*4096
  float* pstats = pctx + (size_t)TQCAP * H * SPLITK * 4096;  // *128

  hipMemsetAsync(cnt, 0, 18 * sizeof(int), stream);
  count_kernel<<<(N + M + 255) / 256, 256, 0, stream>>>(lbl1, N, lbl2, M, cnt);
  offsets_kernel<<<1, 1, 0, stream>>>(cnt, off, pqo, pko, tq, tk, ntl);
  dim3 sgrid(NLBL, 2);
  scatter_kernel<<<sgrid, 1024, 0, stream>>>(lbl1, N, lbl2, M, off, korder, qorder);

  transW_kernel<<<dim3(16, 28), 256, 0, stream>>>(Wq, Wk, Wv, Wf, Wqt, Wkt, Wvt, Wft);

  int gx = (TQCAP > TKCAP) ? TQCAP : TKCAP;
  gemm_in_kernel<<<dim3(gx, 3), 256, 0, stream>>>(
      query, key, value, Wqt, Wkt, Wvt, bq, bk, bv,
      qorder, korder, off, cnt, pqo, pko, tq, tk, ntl, qbuf, kbuf, vbuf);

  attn_mfma<<<dim3(TQCAP, H, SPLITK), 256, 0, stream>>>(
      qbuf, kbuf, vbuf, cnt, tq, ntl, pko, pctx, pstats);

  attn_reduce<<<dim3(TQCAP, H), 256, 0, stream>>>(pctx, pstats, cnt, tq, ntl, cg);

  proj_ln_kernel<<<dim3(TQCAP, 2), 256, 0, stream>>>(
      cg, Wft, bf_, query, qorder, off, cnt, pqo, tq, ntl, gamma, beta, out);
}

// Round 6
// 104.892 us; speedup vs baseline: 49.5086x; 1.4324x over previous
//
#include <hip/hip_runtime.h>
#include <hip/hip_bf16.h>

#define D 256
#define H 4
#define DPH 64
#define NLBL 9
#define SPLITK 4

typedef __attribute__((ext_vector_type(8))) __bf16 bf16x8;
typedef __attribute__((ext_vector_type(8))) unsigned short u16x8;
typedef __attribute__((ext_vector_type(4))) float f32x4;

__device__ __forceinline__ int sw_idx(int row, int col) {
  // ushort-unit index into a [64][64] bf16 LDS tile, XOR-swizzled.
  return row * 64 + (col ^ ((row & 7) << 3));
}

__device__ __forceinline__ unsigned int pk2(float a, float b) {
  unsigned int lo = (unsigned int)__builtin_bit_cast(unsigned short, (__bf16)a);
  unsigned int hi = (unsigned int)__builtin_bit_cast(unsigned short, (__bf16)b);
  return lo | (hi << 16);
}

__device__ __forceinline__ bf16x8 cvt8(float4 u0, float4 u1) {
  bf16x8 r;
  r[0] = (__bf16)u0.x; r[1] = (__bf16)u0.y; r[2] = (__bf16)u0.z; r[3] = (__bf16)u0.w;
  r[4] = (__bf16)u1.x; r[5] = (__bf16)u1.y; r[6] = (__bf16)u1.z; r[7] = (__bf16)u1.w;
  return r;
}

// ---------------------------------------------------------------------------
// Histogram via ballot (no global atomic contention). grid=2 (keys, queries).
// ---------------------------------------------------------------------------
__global__ __launch_bounds__(1024) void hist_kernel(
    const int* __restrict__ lbl1, int n1, const int* __restrict__ lbl2, int n2,
    int* __restrict__ cnt) {
  const int a = blockIdx.x;
  const int n = (a == 0) ? n1 : n2;
  const int* lbl = (a == 0) ? lbl1 : lbl2;
  const int t = threadIdx.x, lane = t & 63;

  __shared__ int bins[NLBL];
  if (t < NLBL) bins[t] = 0;
  __syncthreads();

  for (int chunk = 0; chunk < n; chunk += 1024) {
    int i = chunk + t;
    int l = (i < n) ? lbl[i] : -1;
#pragma unroll
    for (int lab = 0; lab < NLBL; ++lab) {
      unsigned long long bal = __ballot(l == lab);
      if (lane == 0 && bal) atomicAdd(&bins[lab], __popcll(bal));
    }
  }
  __syncthreads();
  if (t < NLBL) cnt[a * NLBL + t] = bins[t];
}

__global__ void offsets_kernel(const int* __restrict__ cnt, int* __restrict__ off,
                               int* __restrict__ pqo, int* __restrict__ pko,
                               int* __restrict__ tq, int* __restrict__ tk,
                               int* __restrict__ ntl) {
  if (threadIdx.x != 0) return;
  int a0 = 0, a1 = 0, p0 = 0, p1 = 0, t0 = 0, t1 = 0;
  for (int l = 0; l < NLBL; ++l) {
    off[l] = a0;      a0 += cnt[l];
    off[10 + l] = a1; a1 += cnt[NLBL + l];
    pko[l] = p0; pqo[l] = p1;
    int tkl = (cnt[l] + 63) >> 6, tql = (cnt[NLBL + l] + 63) >> 6;
    for (int i = 0; i < tkl; ++i) { tk[2 * t0] = l; tk[2 * t0 + 1] = p0 + (i << 6); ++t0; }
    for (int i = 0; i < tql; ++i) { tq[2 * t1] = l; tq[2 * t1 + 1] = p1 + (i << 6); ++t1; }
    p0 += tkl << 6; p1 += tql << 6;
  }
  off[9] = a0; off[19] = a1; pko[9] = p0; pqo[9] = p1;
  ntl[0] = t1; ntl[1] = t0;
}

__global__ __launch_bounds__(1024) void scatter_kernel(
    const int* __restrict__ lbl1, int n1, const int* __restrict__ lbl2, int n2,
    const int* __restrict__ off, int* __restrict__ korder, int* __restrict__ qorder) {
  const int l = blockIdx.x;
  const int a = blockIdx.y;
  const int n = (a == 0) ? n1 : n2;
  const int* lbl = (a == 0) ? lbl1 : lbl2;
  int* order = (a == 0) ? korder : qorder;
  const int base = off[a * 10 + l];

  const int t = threadIdx.x, wave = t >> 6, lane = t & 63;
  __shared__ int wtot[16];
  int pos = 0;
  for (int chunk = 0; chunk < n; chunk += 1024) {
    int i = chunk + t;
    bool flag = (i < n) && (lbl[i] == l);
    unsigned long long bal = __ballot(flag);
    int wprefix = __popcll(bal & ((1ull << lane) - 1ull));
    if (lane == 0) wtot[wave] = __popcll(bal);
    __syncthreads();
    int prew = 0, tot = 0;
#pragma unroll
    for (int w = 0; w < 16; ++w) {
      prew += (w < wave) ? wtot[w] : 0;
      tot += wtot[w];
    }
    if (flag) order[base + pos + prew + wprefix] = i;
    pos += tot;
    __syncthreads();
  }
}

// ---------------------------------------------------------------------------
// Transpose+cast weights: Wt[n][k] = bf16(W[k][n]).
// ---------------------------------------------------------------------------
__global__ __launch_bounds__(256) void transW_kernel(
    const float* __restrict__ Wq, const float* __restrict__ Wk,
    const float* __restrict__ Wv, const float* __restrict__ Wf,
    __bf16* __restrict__ Wqt, __bf16* __restrict__ Wkt,
    __bf16* __restrict__ Wvt, __bf16* __restrict__ Wft) {
  int m = blockIdx.y, sub = blockIdx.x;
  const float* src; __bf16* dst;
  if (m < 9)       { src = Wq + (size_t)m * 65536;        dst = Wqt + (size_t)m * 65536; }
  else if (m < 18) { src = Wk + (size_t)(m - 9) * 65536;  dst = Wkt + (size_t)(m - 9) * 65536; }
  else if (m < 27) { src = Wv + (size_t)(m - 18) * 65536; dst = Wvt + (size_t)(m - 18) * 65536; }
  else             { src = Wf;                            dst = Wft; }
  int k0 = (sub >> 2) << 6, n0 = (sub & 3) << 6;
  __shared__ float lds[64][65];
  int t = threadIdx.x, rr = t >> 6, c = t & 63;
#pragma unroll
  for (int i = 0; i < 16; ++i) {
    int r = i * 4 + rr;
    lds[r][c] = src[(size_t)(k0 + r) * D + n0 + c];
  }
  __syncthreads();
#pragma unroll
  for (int i = 0; i < 16; ++i) {
    int r = i * 4 + rr;
    dst[(size_t)(n0 + r) * D + k0 + c] = (__bf16)lds[c][r];
  }
}

// ---------------------------------------------------------------------------
// Label-routed input projections via MFMA bf16 -> bf16 sorted-padded buffers.
// 32-row x 256-col tiles (2x blocks vs 64-row for latency hiding).
// Query branch pre-scales by 0.25*log2(e) so attention uses exp2 directly.
// ---------------------------------------------------------------------------
__global__ __launch_bounds__(256) void gemm_in_kernel(
    const float* __restrict__ query, const float* __restrict__ key,
    const float* __restrict__ value,
    const __bf16* __restrict__ Wqt, const __bf16* __restrict__ Wkt,
    const __bf16* __restrict__ Wvt,
    const float* __restrict__ bq, const float* __restrict__ bk,
    const float* __restrict__ bv,
    const int* __restrict__ qorder, const int* __restrict__ korder,
    const int* __restrict__ off, const int* __restrict__ cnt,
    const int* __restrict__ pqo, const int* __restrict__ pko,
    const int* __restrict__ tq, const int* __restrict__ tk,
    const int* __restrict__ ntl,
    __bf16* __restrict__ qbuf, __bf16* __restrict__ kbuf, __bf16* __restrict__ vbuf) {
  const int y = blockIdx.y;
  const int nt = (y == 0) ? ntl[0] : ntl[1];
  const int ti = blockIdx.x >> 1, half = blockIdx.x & 1;
  if (ti >= nt) return;
  const int* tt = (y == 0) ? tq : tk;
  const float* x = (y == 0) ? query : (y == 1 ? key : value);
  const __bf16* W = (y == 0) ? Wqt : (y == 1 ? Wkt : Wvt);
  const float* bias = (y == 0) ? bq : (y == 1 ? bk : bv);
  const int* order = (y == 0) ? qorder : korder;
  const int* po = (y == 0) ? pqo : pko;
  __bf16* outp = (y == 0) ? qbuf : (y == 1 ? kbuf : vbuf);
  const float sc = (y == 0) ? 0.36067376f : 1.0f;   // 0.25 * log2(e)

  const int l = tt[2 * ti], prow0 = tt[2 * ti + 1] + half * 32;
  const int cl = (y == 0) ? cnt[NLBL + l] : cnt[l];
  const int ooff = (y == 0) ? off[10 + l] : off[l];
  const int base = prow0 - po[l];

  const int t = threadIdx.x, w = t >> 6, lane = t & 63;
  const int lr = lane & 15, lk = lane >> 4;

  int src[2];
#pragma unroll
  for (int fi = 0; fi < 2; ++fi) {
    int ridx = base + fi * 16 + lr;
    src[fi] = (ridx < cl) ? order[ooff + ridx] : -1;
  }

  bf16x8 az;
#pragma unroll
  for (int j = 0; j < 8; ++j) az[j] = (__bf16)0.f;

  f32x4 acc[2][4];
#pragma unroll
  for (int i = 0; i < 2; ++i)
#pragma unroll
    for (int j = 0; j < 4; ++j) acc[i][j] = (f32x4){0.f, 0.f, 0.f, 0.f};

  for (int kb = 0; kb < 8; ++kb) {
    const int kbase = kb * 32 + lk * 8;
    bf16x8 a[2], b[4];
#pragma unroll
    for (int fi = 0; fi < 2; ++fi) {
      if (src[fi] >= 0) {
        const float* ap = x + (size_t)src[fi] * D + kbase;
        float4 u0 = *(const float4*)ap;
        float4 u1 = *(const float4*)(ap + 4);
        a[fi] = cvt8(u0, u1);
      } else {
        a[fi] = az;
      }
    }
#pragma unroll
    for (int fj = 0; fj < 4; ++fj) {
      int col = w * 64 + fj * 16 + lr;
      b[fj] = *(const bf16x8*)(W + (size_t)l * 65536 + (size_t)col * D + kbase);
    }
#pragma unroll
    for (int fi = 0; fi < 2; ++fi)
#pragma unroll
      for (int fj = 0; fj < 4; ++fj)
        acc[fi][fj] = __builtin_amdgcn_mfma_f32_16x16x32_bf16(a[fi], b[fj], acc[fi][fj], 0, 0, 0);
  }

#pragma unroll
  for (int fj = 0; fj < 4; ++fj) {
    int col = w * 64 + fj * 16 + lr;
    float bv_ = bias[l * D + col];
#pragma unroll
    for (int fi = 0; fi < 2; ++fi)
#pragma unroll
      for (int r = 0; r < 4; ++r) {
        int row = prow0 + fi * 16 + lk * 4 + r;
        outp[(size_t)row * D + col] = (__bf16)((acc[fi][fj][r] + bv_) * sc);
      }
  }
}

// ---------------------------------------------------------------------------
// Split-K MFMA flash attention. grid=(TQCAP, H, SPLITK); tile-table driven.
// Writes unnormalized partials (fp32 ctx + m,l in exp2 domain) to ws.
// ---------------------------------------------------------------------------
__global__ __launch_bounds__(256) void attn_mfma(
    const __bf16* __restrict__ qbuf, const __bf16* __restrict__ kbuf,
    const __bf16* __restrict__ vbuf, const int* __restrict__ cnt,
    const int* __restrict__ tq, const int* __restrict__ ntl,
    const int* __restrict__ pko,
    float* __restrict__ pctx, float* __restrict__ pstats) {
  const int tqi = blockIdx.x;
  if (tqi >= ntl[0]) return;
  const int l = tq[2 * tqi], prow0 = tq[2 * tqi + 1];
  const int h = blockIdx.y, s = blockIdx.z;
  const int nk = cnt[l];
  const int ntiles = (nk + 63) >> 6;
  const int ntsz = (ntiles + SPLITK - 1) / SPLITK;
  const int tt0 = s * ntsz;
  const int tt1 = min(ntiles, tt0 + ntsz);
  if (tt0 >= tt1) return;

  const int t = threadIdx.x;
  const int w = t >> 6, lane = t & 63;
  const int lr = lane & 15, lk = lane >> 4;

  __shared__ __align__(16) unsigned short ks[4096];    // K tile [key][d]
  __shared__ __align__(16) unsigned short vtl[4096];   // V tile [d][key]
  __shared__ __align__(16) unsigned short plds[4096];  // P [wave][q][key]

  const int qloc = w * 16 + lr;
  const int qrow = prow0 + qloc;
  bf16x8 b_q[2];
#pragma unroll
  for (int kb = 0; kb < 2; ++kb)
    b_q[kb] = *(const bf16x8*)(qbuf + (size_t)qrow * D + h * DPH + kb * 32 + lk * 8);

  f32x4 acc_o[4];
#pragma unroll
  for (int i = 0; i < 4; ++i) acc_o[i] = (f32x4){0.f, 0.f, 0.f, 0.f};
  float mrun = -3.4e38f, lrun = 0.f;
  const int kb0 = pko[l];

  for (int tt = tt0; tt < tt1; ++tt) {
    const int n0 = tt << 6;
    __syncthreads();
    // ---- stage K tile (bf16 -> swizzled LDS), 32B per thread
    {
      int row = t >> 2, c0 = (t & 3) * 16;
      const uint4* kp = (const uint4*)(kbuf + (size_t)(kb0 + n0 + row) * D + h * DPH + c0);
      uint4 k0 = kp[0], k1 = kp[1];
      *(uint4*)&ks[sw_idx(row, c0)] = k0;
      *(uint4*)&ks[sw_idx(row, c0 + 8)] = k1;
    }
    // ---- stage V tile transposed (pack key pairs into u32)
    {
      int key2 = (t & 31) * 2, d0 = (t >> 5) * 8;
      const unsigned short* vp = (const unsigned short*)(vbuf + (size_t)(kb0 + n0 + key2) * D + h * DPH + d0);
      u16x8 va = *(const u16x8*)vp;
      u16x8 vb = *(const u16x8*)(vp + D);
#pragma unroll
      for (int j = 0; j < 8; ++j) {
        unsigned int u = (unsigned int)va[j] | ((unsigned int)vb[j] << 16);
        *(unsigned int*)&vtl[sw_idx(d0 + j, key2)] = u;
      }
    }
    __syncthreads();

    // ---- S^T = K x Q^T : C[key][q], key = fi*16 + lk*4 + r, q = lr
    f32x4 s_acc[4];
    const f32x4 zz = {0.f, 0.f, 0.f, 0.f};
#pragma unroll
    for (int fi = 0; fi < 4; ++fi) {
      bf16x8 a0 = *(const bf16x8*)&ks[sw_idx(fi * 16 + lr, lk * 8)];
      s_acc[fi] = __builtin_amdgcn_mfma_f32_16x16x32_bf16(a0, b_q[0], zz, 0, 0, 0);
    }
#pragma unroll
    for (int fi = 0; fi < 4; ++fi) {
      bf16x8 a1 = *(const bf16x8*)&ks[sw_idx(fi * 16 + lr, 32 + lk * 8)];
      s_acc[fi] = __builtin_amdgcn_mfma_f32_16x16x32_bf16(a1, b_q[1], s_acc[fi], 0, 0, 0);
    }

    // ---- online softmax in exp2 domain (logits pre-scaled in qbuf)
    float p[16];
    float tm = -3.4e38f;
#pragma unroll
    for (int fi = 0; fi < 4; ++fi)
#pragma unroll
      for (int r = 0; r < 4; ++r) {
        int key = n0 + fi * 16 + lk * 4 + r;
        float v = (key < nk) ? s_acc[fi][r] : -1e30f;
        p[fi * 4 + r] = v;
        tm = fmaxf(tm, v);
      }
    tm = fmaxf(tm, __shfl_xor(tm, 16, 64));
    tm = fmaxf(tm, __shfl_xor(tm, 32, 64));
    float mnew = fmaxf(mrun, tm);
    float alpha = exp2f(mrun - mnew);
    lrun *= alpha;
#pragma unroll
    for (int fi = 0; fi < 4; ++fi) acc_o[fi] = acc_o[fi] * alpha;
    float ts = 0.f;
#pragma unroll
    for (int i = 0; i < 16; ++i) { p[i] = exp2f(p[i] - mnew); ts += p[i]; }
    ts += __shfl_xor(ts, 16, 64);
    ts += __shfl_xor(ts, 32, 64);
    lrun += ts;
    mrun = mnew;

    // ---- P -> per-wave LDS
#pragma unroll
    for (int fi = 0; fi < 4; ++fi) {
      unsigned int w0 = pk2(p[fi * 4 + 0], p[fi * 4 + 1]);
      unsigned int w1 = pk2(p[fi * 4 + 2], p[fi * 4 + 3]);
      int idx = w * 1024 + sw_idx(lr, fi * 16 + lk * 4);
      *(uint2*)&plds[idx] = make_uint2(w0, w1);
    }

    // ---- O^T += V^T x P : C[d][q], d = fi*16 + lk*4 + r
#pragma unroll
    for (int kb = 0; kb < 2; ++kb) {
      bf16x8 bp = *(const bf16x8*)&plds[w * 1024 + sw_idx(lr, kb * 32 + lk * 8)];
#pragma unroll
      for (int fi = 0; fi < 4; ++fi) {
        bf16x8 av = *(const bf16x8*)&vtl[sw_idx(fi * 16 + lr, kb * 32 + lk * 8)];
        acc_o[fi] = __builtin_amdgcn_mfma_f32_16x16x32_bf16(av, bp, acc_o[fi], 0, 0, 0);
      }
    }
  }

  // ---- write partials
  const size_t base = ((size_t)tqi * H + h) * SPLITK + s;
  float* pc = pctx + base * 4096;
#pragma unroll
  for (int fi = 0; fi < 4; ++fi)
    *(f32x4*)(pc + qloc * 64 + fi * 16 + lk * 4) = acc_o[fi];
  if (lk == 0) {
    pstats[base * 128 + qloc * 2] = mrun;
    pstats[base * 128 + qloc * 2 + 1] = lrun;
  }
}

// ---------------------------------------------------------------------------
// Merge split-K partials, normalize, write cg (bf16). grid=(TQCAP, H).
// ---------------------------------------------------------------------------
__global__ __launch_bounds__(256) void attn_reduce(
    const float* __restrict__ pctx, const float* __restrict__ pstats,
    const int* __restrict__ cnt, const int* __restrict__ tq,
    const int* __restrict__ ntl, __bf16* __restrict__ cg) {
  const int tqi = blockIdx.x;
  if (tqi >= ntl[0]) return;
  const int l = tq[2 * tqi], prow0 = tq[2 * tqi + 1];
  const int h = blockIdx.y;
  const int t = threadIdx.x;
  const int q = t >> 2, part = t & 3;

  __bf16* op = cg + (size_t)(prow0 + q) * D + h * DPH + part * 16;

  const int nk = cnt[l];
  const int ntiles = (nk + 63) >> 6;
  float o[16];
#pragma unroll
  for (int j = 0; j < 16; ++j) o[j] = 0.f;

  if (ntiles > 0) {
    const int ntsz = (ntiles + SPLITK - 1) / SPLITK;
    const int nsp = (ntiles + ntsz - 1) / ntsz;
    const size_t base0 = ((size_t)tqi * H + h) * SPLITK;

    float m = -3.4e38f;
    for (int s = 0; s < nsp; ++s)
      m = fmaxf(m, pstats[(base0 + s) * 128 + q * 2]);
    float L = 0.f;
    float wgt[SPLITK];
    for (int s = 0; s < nsp; ++s) {
      float ms = pstats[(base0 + s) * 128 + q * 2];
      float ls = pstats[(base0 + s) * 128 + q * 2 + 1];
      wgt[s] = exp2f(ms - m);
      L += ls * wgt[s];
    }
    float inv = (L > 0.f) ? (1.f / L) : 0.f;
    for (int s = 0; s < nsp; ++s) {
      const float* pc = pctx + (base0 + s) * 4096 + q * 64 + part * 16;
      float wg = wgt[s] * inv;
#pragma unroll
      for (int j = 0; j < 16; ++j) o[j] += pc[j] * wg;
    }
  }

  uint4 o0, o1;
  o0.x = pk2(o[0], o[1]);  o0.y = pk2(o[2], o[3]);
  o0.z = pk2(o[4], o[5]);  o0.w = pk2(o[6], o[7]);
  o1.x = pk2(o[8], o[9]);  o1.y = pk2(o[10], o[11]);
  o1.z = pk2(o[12], o[13]); o1.w = pk2(o[14], o[15]);
  *(uint4*)op = o0;
  *(uint4*)(op + 8) = o1;
}

// ---------------------------------------------------------------------------
// Fused: rbuf = cg @ Wf + bf + query residual -> LayerNorm -> scatter to out.
// grid=(TQCAP, 2), 32 rows per block.
// ---------------------------------------------------------------------------
__global__ __launch_bounds__(256) void proj_ln_kernel(
    const __bf16* __restrict__ cg, const __bf16* __restrict__ Wft,
    const float* __restrict__ bf_, const float* __restrict__ query,
    const int* __restrict__ qorder, const int* __restrict__ off,
    const int* __restrict__ cnt, const int* __restrict__ pqo,
    const int* __restrict__ tq, const int* __restrict__ ntl,
    const float* __restrict__ gamma, const float* __restrict__ beta,
    float* __restrict__ out) {
  const int tqi = blockIdx.x;
  if (tqi >= ntl[0]) return;
  const int l = tq[2 * tqi];
  const int prow0 = tq[2 * tqi + 1] + blockIdx.y * 32;
  const int cl = cnt[NLBL + l];
  const int ooff = off[10 + l];
  const int base = prow0 - pqo[l];

  const int t = threadIdx.x, w = t >> 6, lane = t & 63;
  const int lr = lane & 15, lk = lane >> 4;

  __shared__ int srcs[32];
  __shared__ float psum[4][32], psum2[4][32];
  __shared__ float mu_s[32], is_s[32];

  if (t < 32) {
    int ridx = base + t;
    srcs[t] = (ridx < cl) ? qorder[ooff + ridx] : -1;
  }

  f32x4 acc[2][4];
#pragma unroll
  for (int i = 0; i < 2; ++i)
#pragma unroll
    for (int j = 0; j < 4; ++j) acc[i][j] = (f32x4){0.f, 0.f, 0.f, 0.f};

  for (int kb = 0; kb < 8; ++kb) {
    const int kbase = kb * 32 + lk * 8;
    bf16x8 a[2], b[4];
#pragma unroll
    for (int fi = 0; fi < 2; ++fi)
      a[fi] = *(const bf16x8*)(cg + (size_t)(prow0 + fi * 16 + lr) * D + kbase);
#pragma unroll
    for (int fj = 0; fj < 4; ++fj) {
      int col = w * 64 + fj * 16 + lr;
      b[fj] = *(const bf16x8*)(Wft + (size_t)col * D + kbase);
    }
#pragma unroll
    for (int fi = 0; fi < 2; ++fi)
#pragma unroll
      for (int fj = 0; fj < 4; ++fj)
        acc[fi][fj] = __builtin_amdgcn_mfma_f32_16x16x32_bf16(a[fi], b[fj], acc[fi][fj], 0, 0, 0);
  }

  __syncthreads();  // srcs ready

  float res[2][4][4];
  float s1[2][4], s2[2][4];
#pragma unroll
  for (int fi = 0; fi < 2; ++fi)
#pragma unroll
    for (int r = 0; r < 4; ++r) { s1[fi][r] = 0.f; s2[fi][r] = 0.f; }

#pragma unroll
  for (int fj = 0; fj < 4; ++fj) {
    int col = w * 64 + fj * 16 + lr;
    float bcol = bf_[col];
#pragma unroll
    for (int fi = 0; fi < 2; ++fi)
#pragma unroll
      for (int r = 0; r < 4; ++r) {
        int rowl = fi * 16 + lk * 4 + r;
        int sr = srcs[rowl];
        float qv = (sr >= 0) ? query[(size_t)sr * D + col] : 0.f;
        float v = acc[fi][fj][r] + bcol + qv;
        res[fi][fj][r] = v;
        s1[fi][r] += v;
        s2[fi][r] += v * v;
      }
  }

#pragma unroll
  for (int o2 = 1; o2 <= 8; o2 <<= 1) {
#pragma unroll
    for (int fi = 0; fi < 2; ++fi)
#pragma unroll
      for (int r = 0; r < 4; ++r) {
        s1[fi][r] += __shfl_xor(s1[fi][r], o2, 64);
        s2[fi][r] += __shfl_xor(s2[fi][r], o2, 64);
      }
  }
  if (lr == 0) {
#pragma unroll
    for (int fi = 0; fi < 2; ++fi)
#pragma unroll
      for (int r = 0; r < 4; ++r) {
        int rowl = fi * 16 + lk * 4 + r;
        psum[w][rowl] = s1[fi][r];
        psum2[w][rowl] = s2[fi][r];
      }
  }
  __syncthreads();
  if (t < 32) {
    float tot = psum[0][t] + psum[1][t] + psum[2][t] + psum[3][t];
    float tot2 = psum2[0][t] + psum2[1][t] + psum2[2][t] + psum2[3][t];
    float mu = tot * (1.f / D);
    float var = tot2 * (1.f / D) - mu * mu;
    mu_s[t] = mu;
    is_s[t] = rsqrtf(var + 1e-5f);
  }
  __syncthreads();

#pragma unroll
  for (int fj = 0; fj < 4; ++fj) {
    int col = w * 64 + fj * 16 + lr;
    float gc = gamma[col], bc = beta[col];
#pragma unroll
    for (int fi = 0; fi < 2; ++fi)
#pragma unroll
      for (int r = 0; r < 4; ++r) {
        int rowl = fi * 16 + lk * 4 + r;
        int sr = srcs[rowl];
        if (sr >= 0)
          out[(size_t)sr * D + col] =
              (res[fi][fj][r] - mu_s[rowl]) * is_s[rowl] * gc + bc;
      }
  }
}

// ---------------------------------------------------------------------------
extern "C" void kernel_launch(void* const* d_in, const int* in_sizes, int n_in,
                              void* d_out, int out_size, void* d_ws, size_t ws_size,
                              hipStream_t stream) {
  const float* key   = (const float*)d_in[0];
  const float* value = (const float*)d_in[1];
  const float* query = (const float*)d_in[2];
  const int*   lbl1  = (const int*)d_in[3];
  const int*   lbl2  = (const int*)d_in[4];
  const float* Wq = (const float*)d_in[5];
  const float* bq = (const float*)d_in[6];
  const float* Wk = (const float*)d_in[7];
  const float* bk = (const float*)d_in[8];
  const float* Wv = (const float*)d_in[9];
  const float* bv = (const float*)d_in[10];
  const float* Wf = (const float*)d_in[11];
  const float* bf_ = (const float*)d_in[12];
  const float* gamma = (const float*)d_in[13];
  const float* beta  = (const float*)d_in[14];
  float* out = (float*)d_out;

  const int N = in_sizes[0] / D;
  const int M = in_sizes[2] / D;
  const int MP = M + NLBL * 64;
  const int NP = N + NLBL * 64;
  const int TQCAP = (M + 63) / 64 + NLBL;
  const int TKCAP = (N + 63) / 64 + NLBL;

  int* cnt = (int*)d_ws;
  int* off = cnt + 32;
  int* pqo = off + 32;
  int* pko = pqo + 16;
  int* ntl = pko + 16;
  int* tq  = ntl + 16;
  int* tk  = tq + 2 * TQCAP;
  int* korder = tk + 2 * TKCAP;
  int* qorder = korder + N;
  size_t ihdr = (((size_t)(112 + 2 * TQCAP + 2 * TKCAP + N + M)) * 4 + 255) & ~(size_t)255;

  __bf16* Wqt = (__bf16*)((char*)d_ws + ihdr);
  __bf16* Wkt = Wqt + (size_t)9 * 65536;
  __bf16* Wvt = Wkt + (size_t)9 * 65536;
  __bf16* Wft = Wvt + (size_t)9 * 65536;
  __bf16* cg  = Wft + 65536;                       // MP*D
  __bf16* qbuf = cg + (size_t)MP * D;
  __bf16* kbuf = qbuf + (size_t)MP * D;
  __bf16* vbuf = kbuf + (size_t)NP * D;
  float* pctx = (float*)(vbuf + (size_t)NP * D);   // TQCAP*H*SPLITK*4096
  float* pstats = pctx + (size_t)TQCAP * H * SPLITK * 4096;  // *128

  hist_kernel<<<2, 1024, 0, stream>>>(lbl1, N, lbl2, M, cnt);
  offsets_kernel<<<1, 1, 0, stream>>>(cnt, off, pqo, pko, tq, tk, ntl);
  dim3 sgrid(NLBL, 2);
  scatter_kernel<<<sgrid, 1024, 0, stream>>>(lbl1, N, lbl2, M, off, korder, qorder);

  transW_kernel<<<dim3(16, 28), 256, 0, stream>>>(Wq, Wk, Wv, Wf, Wqt, Wkt, Wvt, Wft);

  int gx = (TQCAP > TKCAP) ? TQCAP : TKCAP;
  gemm_in_kernel<<<dim3(gx * 2, 3), 256, 0, stream>>>(
      query, key, value, Wqt, Wkt, Wvt, bq, bk, bv,
      qorder, korder, off, cnt, pqo, pko, tq, tk, ntl, qbuf, kbuf, vbuf);

  attn_mfma<<<dim3(TQCAP, H, SPLITK), 256, 0, stream>>>(
      qbuf, kbuf, vbuf, cnt, tq, ntl, pko, pctx, pstats);

  attn_reduce<<<dim3(TQCAP, H), 256, 0, stream>>>(pctx, pstats, cnt, tq, ntl, cg);

  proj_ln_kernel<<<dim3(TQCAP, 2), 256, 0, stream>>>(
      cg, Wft, bf_, query, qorder, off, cnt, pqo, tq, ntl, gamma, beta, out);
}